// Round 9
// baseline (136.187 us; speedup 1.0000x reference)
//
#include <hip/hip_runtime.h>
#include <hip/hip_bf16.h>
#include <stdint.h>

// Sizes (fixed for this problem)
#define NHEADS 16
#define HDIM   64
#define DMODEL 1024
#define SEQ    2048
#define NB     2
#define MTOT   (NB*SEQ)     // 4096 rows of x
#define NTOT   (3*DMODEL)   // 3072 qkv cols
#define KTOT   DMODEL       // 1024

// fold (1/8)*log2(e) into Q so softmax runs in exp2 domain
#define QSCALE 0.18033688011112042f

typedef __attribute__((ext_vector_type(8)))  short          bf16x8;
typedef __attribute__((ext_vector_type(4)))  float          f32x4;
typedef __attribute__((ext_vector_type(8)))  unsigned short u16x8;

__device__ __forceinline__ unsigned short f2bf(float f) {
  unsigned u = __builtin_bit_cast(unsigned, f);
  u += 0x7fffu + ((u >> 16) & 1u);          // round-to-nearest-even
  return (unsigned short)(u >> 16);
}

__device__ __forceinline__ f32x4 vmax4(f32x4 a, f32x4 b) {
  f32x4 r;
  r[0]=fmaxf(a[0],b[0]); r[1]=fmaxf(a[1],b[1]);
  r[2]=fmaxf(a[2],b[2]); r[3]=fmaxf(a[3],b[3]);
  return r;
}

__device__ __forceinline__ void async_copy16(void* lds, const void* g) {
  __builtin_amdgcn_global_load_lds(
      (const __attribute__((address_space(1))) unsigned int*)g,
      (__attribute__((address_space(3))) unsigned int*)lds, 16, 0, 0);
}

// ---------------------------------------------------------------- convert x
__global__ void convert_x_kernel(const float* __restrict__ x,
                                 unsigned short* __restrict__ xb) {
  int i = blockIdx.x * 256 + threadIdx.x;
  const f32x4* xv = reinterpret_cast<const f32x4*>(x);
  f32x4 a = xv[2*i];
  f32x4 b = xv[2*i + 1];
  u16x8 r;
  r[0]=f2bf(a[0]); r[1]=f2bf(a[1]); r[2]=f2bf(a[2]); r[3]=f2bf(a[3]);
  r[4]=f2bf(b[0]); r[5]=f2bf(b[1]); r[6]=f2bf(b[2]); r[7]=f2bf(b[3]);
  reinterpret_cast<u16x8*>(xb)[i] = r;
}

// --------------------------------------- transpose + permute + convert W
__global__ void transpose_w_kernel(const float* __restrict__ W,
                                   unsigned short* __restrict__ Wt) {
  __shared__ float tile[64][65];
  int j0 = blockIdx.x * 64;
  int k0 = blockIdx.y * 64;
  int tid = threadIdx.x;
  int lr = tid >> 6;
  int lc = tid & 63;
  #pragma unroll
  for (int i = 0; i < 16; ++i) {
    int r = i*4 + lr;
    tile[r][lc] = W[(size_t)(k0 + r)*NTOT + j0 + lc];
  }
  __syncthreads();
  #pragma unroll
  for (int i = 0; i < 16; ++i) {
    int jr = i*4 + lr;
    int j  = j0 + jr;
    int oc = (j % 3)*DMODEL + (j / 3);
    Wt[(size_t)oc*KTOT + k0 + lc] = f2bf(tile[lc][jr]);
  }
}

// ---------------------------------------------------------------- QKV GEMM
// R9: T3-minimum 2-phase double-buffered staging (prefetch t+1 into buf^1
// before computing t; the end-of-iter __syncthreads (implicit vmcnt(0))
// drains the prefetch). + T1 XCD-bijective grid swizzle (768 % 8 == 0).
// No T2 LDS swizzle: guide regime-gate says T2 is null at 2-phase.
#define BM 128
#define BN 128
#define BK 64
#define NBX (NTOT/BN)    // 24
#define NBY (MTOT/BM)    // 32
__launch_bounds__(256)
__global__ void qkv_gemm_kernel(const unsigned short* __restrict__ xb,
                                const unsigned short* __restrict__ wt,
                                const float* __restrict__ bqkv,
                                unsigned short* __restrict__ Qb,
                                unsigned short* __restrict__ Kb,
                                unsigned short* __restrict__ Vt) {
  __shared__ __align__(16) unsigned short As[2][BM*BK];
  __shared__ __align__(16) unsigned short Bs[2][BN*BK];
  int tid = threadIdx.x;
  int w = tid >> 6, l = tid & 63;

  // XCD swizzle: 768 blocks, 8 XCDs, 96 contiguous tiles per XCD
  int bid = blockIdx.y * NBX + blockIdx.x;
  int swz = (bid & 7) * (NBX*NBY/8) + (bid >> 3);
  int m0 = (swz / NBX) * BM;
  int n0 = (swz % NBX) * BN;

  int lrow = l >> 3;
  int lcol = (l & 7) * 8;
  int wm = (w >> 1) * 64;
  int wn = (w & 1) * 64;
  int ln = l & 15, lg = l >> 4;

  f32x4 acc[4][4];
  const f32x4 zero4 = {0.f, 0.f, 0.f, 0.f};
  #pragma unroll
  for (int i = 0; i < 4; ++i)
    #pragma unroll
    for (int j = 0; j < 4; ++j) acc[i][j] = zero4;

  // STAGE K-tile KT into buffer BUF (8 global_load_lds per thread)
  #define STAGEG(BUF, KT)                                                     \
  do {                                                                        \
    int k0_ = (KT) * BK;                                                      \
    _Pragma("unroll")                                                         \
    for (int i = 0; i < 4; ++i) {                                             \
      int rbase = w*32 + i*8;                                                 \
      async_copy16(&As[BUF][rbase*BK],                                        \
                   &xb[(size_t)(m0 + rbase + lrow)*KTOT + k0_ + lcol]);       \
      async_copy16(&Bs[BUF][rbase*BK],                                        \
                   &wt[(size_t)(n0 + rbase + lrow)*KTOT + k0_ + lcol]);       \
    }                                                                         \
  } while (0)

  STAGEG(0, 0);
  asm volatile("s_waitcnt vmcnt(0)" ::: "memory");
  __syncthreads();

  for (int kt = 0; kt < KTOT/BK; ++kt) {
    int cur = kt & 1;
    if (kt < KTOT/BK - 1) STAGEG(cur ^ 1, kt + 1);   // prefetch next tile

    #pragma unroll
    for (int ks = 0; ks < 2; ++ks) {
      bf16x8 af[4], bfr[4];
      #pragma unroll
      for (int mi = 0; mi < 4; ++mi)
        af[mi] = *reinterpret_cast<const bf16x8*>(&As[cur][(wm + mi*16 + ln)*BK + ks*32 + lg*8]);
      #pragma unroll
      for (int ni = 0; ni < 4; ++ni)
        bfr[ni] = *reinterpret_cast<const bf16x8*>(&Bs[cur][(wn + ni*16 + ln)*BK + ks*32 + lg*8]);
      #pragma unroll
      for (int mi = 0; mi < 4; ++mi)
        #pragma unroll
        for (int ni = 0; ni < 4; ++ni)
          acc[mi][ni] = __builtin_amdgcn_mfma_f32_16x16x32_bf16(af[mi], bfr[ni], acc[mi][ni], 0, 0, 0);
    }
    __syncthreads();   // implicit vmcnt(0): prefetch landed, LDS reads done
  }
  #undef STAGEG

  int r4 = lg * 4;
  #pragma unroll
  for (int mi = 0; mi < 4; ++mi) {
    #pragma unroll
    for (int ni = 0; ni < 4; ++ni) {
      int nc = n0 + wn + ni*16 + ln;
      int c  = nc >> 10;
      int hd = nc & 1023;
      int h = hd >> 6, d = hd & 63;
      float bias = bqkv[hd*3 + c];
      float qs = (c == 0) ? QSCALE : 1.0f;   // fold softmax scale into Q
      #pragma unroll
      for (int j = 0; j < 4; ++j) {
        int m = m0 + wm + mi*16 + r4 + j;
        int n = m >> 11, t = m & 2047;
        unsigned short val = f2bf((acc[mi][ni][j] + bias) * qs);
        size_t nh = (size_t)(n*NHEADS + h);
        if (c == 0)      Qb[((nh*SEQ + t) << 6) + d] = val;
        else if (c == 1) Kb[((nh*SEQ + t) << 6) + d] = val;
        else             Vt[((nh*HDIM + d) << 11) + t] = val;
      }
    }
  }
}

// ---------------------------------------------------------------- attention
// LDS-staged flash attention (T3 2-phase pipeline), 8-wave blocks.
// Block = 8 waves = 128 q-rows, one head, full 2048-key sweep. K-tile
// [64 keys][64 d] and V-tile [64 d][64 keys] staged to LDS dbuf via
// global_load_lds (width 16), staged ONCE per 128 q-rows. Rule-21 swizzle:
// linear LDS dest + inverse-XOR source (seg ^= row&7) + XOR on ds_read.
// MFMA fragment maps (HW-validated R1/R4/R7):
//   A-frag: row=l&15, k=8*(l>>4)+j   B-frag: col=l&15, k=8*(l>>4)+j
//   C/D   : col=l&15, row=4*(l>>4)+reg
// Softmax: per-lane local max + T13 defer-max; deferred row-sum; P packed
// with v_cvt_pk_bf16_f32 (T12 recipe, RNE); P stride 176B (2-way, free).
#define PROW    88                  // P row stride, bf16 elems (176 B)
#define POFF    32768               // P regions start (after K/V staging)
#define PBYTES  2816                // 16 rows x 176 B per wave
#define OREGION 4352                // epilogue obuf: 16 x 68 f32 (reuses staging)
__launch_bounds__(512)
__global__ void attn_kernel(const unsigned short* __restrict__ Qb,
                            const unsigned short* __restrict__ Kb,
                            const unsigned short* __restrict__ Vt,
                            float* __restrict__ out) {
  __shared__ __align__(16) unsigned char smem[POFF + 8*PBYTES]; // 55296 B
  int tid = threadIdx.x;
  int w = tid >> 6, l = tid & 63;
  int ln = l & 15, lg = l >> 4;

  unsigned short* Pw  = (unsigned short*)(smem + POFF + w * PBYTES);
  float*          obw = (float*)         (smem + w * OREGION); // post-loop only

  // XCD clustering: 512 blocks, 8 XCDs -> each XCD owns 4 heads
  int fid  = blockIdx.x;
  int xcd  = fid & 7, idx = fid >> 3;       // idx 0..63
  int bh   = xcd * 4 + (idx >> 4);          // 0..31
  int qblk = idx & 15;                      // 0..15 (128 q-rows each)
  int q0   = qblk * 128 + w * 16;

  const unsigned short* Qh = Qb + (size_t)bh * SEQ * HDIM;
  const unsigned short* Kh = Kb + (size_t)bh * SEQ * HDIM;
  const unsigned short* Vh = Vt + (size_t)bh * HDIM * SEQ;

  // staging mapping: 512 threads cover one 64x64 bf16 tile in ONE call
  int srow = w*8 + (l >> 3);      // row 0..63
  int sseg = (l & 7) ^ (srow & 7);// inverse-swizzled 16B segment

  // Q B-fragments (col = q = ln), d-windows dw=0,1
  bf16x8 qf[2];
  #pragma unroll
  for (int dw = 0; dw < 2; ++dw)
    qf[dw] = *reinterpret_cast<const bf16x8*>(&Qh[(size_t)(q0 + ln)*HDIM + dw*32 + lg*8]);

  const f32x4 zero4 = {0.f, 0.f, 0.f, 0.f};
  f32x4 o[4];
  #pragma unroll
  for (int db = 0; db < 4; ++db) o[db] = zero4;
  f32x4 psum4 = zero4;
  float mrow = -INFINITY;

  // STAGE one 64-key tile: K[key][d] + V[d][key], inverse-swizzled source
  #define STAGE(BUF, KEY0)                                                    \
  do {                                                                        \
    async_copy16(smem + (BUF)*8192 + w*1024,                                  \
                 &Kh[(size_t)((KEY0) + srow)*HDIM + sseg*8]);                 \
    async_copy16(smem + 16384 + (BUF)*8192 + w*1024,                          \
                 &Vh[(size_t)srow*SEQ + (KEY0) + sseg*8]);                    \
  } while (0)

  STAGE(0, 0);
  __syncthreads();   // drains vmcnt(0): buffer 0 ready

  int xorE = (ln & 7) << 3;   // element-index XOR for swizzled ds_read

  for (int kv = 0; kv < 32; ++kv) {
    int cur  = kv & 1;
    int nkey = (kv < 31) ? (kv + 1) * 64 : kv * 64;
    STAGE(cur ^ 1, nkey);     // prefetch next tile (drained by the barrier)

    const unsigned short* Kc = (const unsigned short*)(smem + cur*8192);
    const unsigned short* Vc = (const unsigned short*)(smem + 16384 + cur*8192);

    // ---- S^T: 4 key-blocks x 2 d-windows (K A-frags from swizzled LDS)
    f32x4 s[4];
    #pragma unroll
    for (int kb = 0; kb < 4; ++kb) {
      int r = kb*16 + ln;
      bf16x8 k0 = *reinterpret_cast<const bf16x8*>(&Kc[r*HDIM + ((     lg*8) ^ xorE)]);
      bf16x8 k1 = *reinterpret_cast<const bf16x8*>(&Kc[r*HDIM + ((32 + lg*8) ^ xorE)]);
      f32x4 t0 = __builtin_amdgcn_mfma_f32_16x16x32_bf16(k0, qf[0], zero4, 0, 0, 0);
      s[kb]    = __builtin_amdgcn_mfma_f32_16x16x32_bf16(k1, qf[1], t0,    0, 0, 0);
    }

    // ---- per-lane local max over this lane's 16 keys (no cross-lane)
    f32x4 m4 = vmax4(vmax4(s[0], s[1]), vmax4(s[2], s[3]));
    float localmax = fmaxf(fmaxf(m4[0], m4[1]), fmaxf(m4[2], m4[3]));

    // ---- T13 defer-max: full reduce+rescale only when max grows (rare)
    if (!__all(localmax <= mrow + 8.f)) {
      float pm = localmax;
      pm = fmaxf(pm, __shfl_xor(pm, 16));
      pm = fmaxf(pm, __shfl_xor(pm, 32));
      float mn  = fmaxf(mrow, pm);
      float scl = __builtin_amdgcn_exp2f(mrow - mn);
      mrow = mn;
      psum4 *= scl;
      #pragma unroll
      for (int db = 0; db < 4; ++db)
        #pragma unroll
        for (int r = 0; r < 4; ++r) o[db][r] *= scl;
    }

    // ---- P = exp2(S - m); accumulate per-lane partial sums in registers
    #pragma unroll
    for (int kb = 0; kb < 4; ++kb) {
      #pragma unroll
      for (int r = 0; r < 4; ++r)
        s[kb][r] = __builtin_amdgcn_exp2f(s[kb][r] - mrow);
      psum4 += s[kb];
    }

    // ---- P -> LDS via v_cvt_pk_bf16_f32 (T12; RNE, same bits as f2bf)
    #pragma unroll
    for (int kb = 0; kb < 4; ++kb) {
      uint2 pk;
      asm("v_cvt_pk_bf16_f32 %0, %1, %2" : "=v"(pk.x) : "v"(s[kb][0]), "v"(s[kb][1]));
      asm("v_cvt_pk_bf16_f32 %0, %1, %2" : "=v"(pk.y) : "v"(s[kb][2]), "v"(s[kb][3]));
      *reinterpret_cast<uint2*>(&Pw[ln*PROW + kb*16 + 4*lg]) = pk;
    }

    // ---- PV: A = V^T frags (swizzled LDS), B = P^T from LDS
    #pragma unroll
    for (int kw = 0; kw < 2; ++kw) {
      bf16x8 pb = *reinterpret_cast<const bf16x8*>(&Pw[ln*PROW + kw*32 + lg*8]);
      #pragma unroll
      for (int db = 0; db < 4; ++db) {
        int r = db*16 + ln;
        bf16x8 vfr = *reinterpret_cast<const bf16x8*>(
            &Vc[r*64 + ((kw*32 + lg*8) ^ xorE)]);
        o[db] = __builtin_amdgcn_mfma_f32_16x16x32_bf16(vfr, pb, o[db], 0, 0, 0);
      }
    }

    __syncthreads();   // drains vmcnt(0) (next buffer staged) + LDS
  }
  #undef STAGE

  // ---- post-loop: row-sum reduce (once), normalize, transpose, store
  float ls = (psum4[0] + psum4[1]) + (psum4[2] + psum4[3]);
  ls += __shfl_xor(ls, 16);
  ls += __shfl_xor(ls, 32);
  float inv = 1.f / ls;

  #pragma unroll
  for (int db = 0; db < 4; ++db)
    #pragma unroll
    for (int r = 0; r < 4; ++r)
      obw[ln*68 + db*16 + 4*lg + r] = o[db][r] * inv;
  asm volatile("s_waitcnt lgkmcnt(0)" ::: "memory");
  int n = bh >> 4, h = bh & 15;
  #pragma unroll
  for (int p = 0; p < 4; ++p) {
    int q = p*4 + lg;
    f32x4 vv = *reinterpret_cast<const f32x4*>(&obw[q*68 + ln*4]);
    *reinterpret_cast<f32x4*>(
        &out[((size_t)(n*SEQ + q0 + q))*DMODEL + h*HDIM + ln*4]) = vv;
  }
}

// ---------------------------------------------------------------- launcher
extern "C" void kernel_launch(void* const* d_in, const int* in_sizes, int n_in,
                              void* d_out, int out_size, void* d_ws, size_t ws_size,
                              hipStream_t stream) {
  const float* x    = (const float*)d_in[0];
  // d_in[1] = mask: constant shift along query axis inside softmax -> no-op
  const float* Wq   = (const float*)d_in[2];
  const float* bq   = (const float*)d_in[3];
  float* out = (float*)d_out;

  unsigned short* xb = (unsigned short*)d_ws;                    // [4096][1024]
  unsigned short* wt = xb + (size_t)MTOT*KTOT;                   // [3072][1024]
  unsigned short* Qb = wt + (size_t)NTOT*KTOT;                   // [32][2048][64]
  unsigned short* Kb = Qb + (size_t)NB*NHEADS*SEQ*HDIM;          // [32][2048][64]
  unsigned short* Vt = Kb + (size_t)NB*NHEADS*SEQ*HDIM;          // [32][64][2048]

  convert_x_kernel<<<(MTOT*KTOT/8)/256, 256, 0, stream>>>(x, xb);
  transpose_w_kernel<<<dim3(NTOT/64, KTOT/64), 256, 0, stream>>>(Wq, wt);
  qkv_gemm_kernel<<<dim3(NBX, NBY), 256, 0, stream>>>(xb, wt, bq, Qb, Kb, Vt);
  attn_kernel<<<512, 512, 0, stream>>>(Qb, Kb, Vt, out);
}

// Round 10
// 124.678 us; speedup vs baseline: 1.0923x; 1.0923x over previous
//
#include <hip/hip_runtime.h>
#include <hip/hip_bf16.h>
#include <stdint.h>

// Sizes (fixed for this problem)
#define NHEADS 16
#define HDIM   64
#define DMODEL 1024
#define SEQ    2048
#define NB     2
#define MTOT   (NB*SEQ)     // 4096 rows of x
#define NTOT   (3*DMODEL)   // 3072 qkv cols
#define KTOT   DMODEL       // 1024

// fold (1/8)*log2(e) into Q so softmax runs in exp2 domain
#define QSCALE 0.18033688011112042f

typedef __attribute__((ext_vector_type(8)))  short          bf16x8;
typedef __attribute__((ext_vector_type(4)))  float          f32x4;
typedef __attribute__((ext_vector_type(8)))  unsigned short u16x8;

__device__ __forceinline__ unsigned short f2bf(float f) {
  unsigned u = __builtin_bit_cast(unsigned, f);
  u += 0x7fffu + ((u >> 16) & 1u);          // round-to-nearest-even
  return (unsigned short)(u >> 16);
}

__device__ __forceinline__ f32x4 vmax4(f32x4 a, f32x4 b) {
  f32x4 r;
  r[0]=fmaxf(a[0],b[0]); r[1]=fmaxf(a[1],b[1]);
  r[2]=fmaxf(a[2],b[2]); r[3]=fmaxf(a[3],b[3]);
  return r;
}

__device__ __forceinline__ void async_copy16(void* lds, const void* g) {
  __builtin_amdgcn_global_load_lds(
      (const __attribute__((address_space(1))) unsigned int*)g,
      (__attribute__((address_space(3))) unsigned int*)lds, 16, 0, 0);
}

// ---------------------------------------------------------------- convert x
__global__ void convert_x_kernel(const float* __restrict__ x,
                                 unsigned short* __restrict__ xb) {
  int i = blockIdx.x * 256 + threadIdx.x;
  const f32x4* xv = reinterpret_cast<const f32x4*>(x);
  f32x4 a = xv[2*i];
  f32x4 b = xv[2*i + 1];
  u16x8 r;
  r[0]=f2bf(a[0]); r[1]=f2bf(a[1]); r[2]=f2bf(a[2]); r[3]=f2bf(a[3]);
  r[4]=f2bf(b[0]); r[5]=f2bf(b[1]); r[6]=f2bf(b[2]); r[7]=f2bf(b[3]);
  reinterpret_cast<u16x8*>(xb)[i] = r;
}

// --------------------------------------- transpose + permute + convert W
__global__ void transpose_w_kernel(const float* __restrict__ W,
                                   unsigned short* __restrict__ Wt) {
  __shared__ float tile[64][65];
  int j0 = blockIdx.x * 64;
  int k0 = blockIdx.y * 64;
  int tid = threadIdx.x;
  int lr = tid >> 6;
  int lc = tid & 63;
  #pragma unroll
  for (int i = 0; i < 16; ++i) {
    int r = i*4 + lr;
    tile[r][lc] = W[(size_t)(k0 + r)*NTOT + j0 + lc];
  }
  __syncthreads();
  #pragma unroll
  for (int i = 0; i < 16; ++i) {
    int jr = i*4 + lr;
    int j  = j0 + jr;
    int oc = (j % 3)*DMODEL + (j / 3);
    Wt[(size_t)oc*KTOT + k0 + lc] = f2bf(tile[lc][jr]);
  }
}

// ---------------------------------------------------------------- QKV GEMM
// R10: natural grid order (R9 XCD swizzle blew per-XCD L2: FETCH +36%).
// Asymmetric dbuf: B double-buffered (prefetch covered by compute), A single
// (drain between the two barriers; A panels are L2-hot across 24 N-blocks).
// LDS 48KB -> 3 blocks/CU, all 768 blocks co-resident (R8 occupancy).
// T2 LDS XOR-swizzle on A and B (linear gload_lds dest + inverse-swizzled
// global source + XOR on ds_read) kills the 16-way stride-128B conflicts.
#define BM 128
#define BN 128
#define BK 64
#define NBX (NTOT/BN)    // 24
#define NBY (MTOT/BM)    // 32
__launch_bounds__(256)
__global__ void qkv_gemm_kernel(const unsigned short* __restrict__ xb,
                                const unsigned short* __restrict__ wt,
                                const float* __restrict__ bqkv,
                                unsigned short* __restrict__ Qb,
                                unsigned short* __restrict__ Kb,
                                unsigned short* __restrict__ Vt) {
  __shared__ __align__(16) unsigned short As[BM*BK];        // 16 KB
  __shared__ __align__(16) unsigned short Bs[2][BN*BK];     // 32 KB
  int tid = threadIdx.x;
  int w = tid >> 6, l = tid & 63;
  int m0 = blockIdx.y * BM;
  int n0 = blockIdx.x * BN;
  int ln = l & 15, lg = l >> 4;
  int wm = (w >> 1) * 64;
  int wn = (w & 1) * 64;
  int xorE = (ln & 7) << 3;   // element-index XOR for swizzled ds_read

  f32x4 acc[4][4];
  const f32x4 zero4 = {0.f, 0.f, 0.f, 0.f};
  #pragma unroll
  for (int i = 0; i < 4; ++i)
    #pragma unroll
    for (int j = 0; j < 4; ++j) acc[i][j] = zero4;

  // stage macros: linear LDS dest, inverse-swizzled global source segment
  #define STAGE_A(KT)                                                         \
  do {                                                                        \
    _Pragma("unroll")                                                         \
    for (int i = 0; i < 4; ++i) {                                             \
      int rbase = w*32 + i*8;                                                 \
      int row   = rbase + (l >> 3);                                           \
      int seg   = (l & 7) ^ (row & 7);                                        \
      async_copy16(&As[rbase*BK],                                             \
                   &xb[(size_t)(m0 + row)*KTOT + (KT)*BK + seg*8]);           \
    }                                                                         \
  } while (0)
  #define STAGE_B(BUF, KT)                                                    \
  do {                                                                        \
    _Pragma("unroll")                                                         \
    for (int i = 0; i < 4; ++i) {                                             \
      int rbase = w*32 + i*8;                                                 \
      int row   = rbase + (l >> 3);                                           \
      int seg   = (l & 7) ^ (row & 7);                                        \
      async_copy16(&Bs[BUF][rbase*BK],                                        \
                   &wt[(size_t)(n0 + row)*KTOT + (KT)*BK + seg*8]);           \
    }                                                                         \
  } while (0)

  STAGE_A(0);
  STAGE_B(0, 0);
  asm volatile("s_waitcnt vmcnt(0)" ::: "memory");
  __syncthreads();

  for (int kt = 0; kt < KTOT/BK; ++kt) {
    int cur = kt & 1;
    if (kt < KTOT/BK - 1) STAGE_B(cur ^ 1, kt + 1);  // covered by compute

    #pragma unroll
    for (int ks = 0; ks < 2; ++ks) {
      bf16x8 af[4], bfr[4];
      #pragma unroll
      for (int mi = 0; mi < 4; ++mi)
        af[mi] = *reinterpret_cast<const bf16x8*>(
            &As[(wm + mi*16 + ln)*BK + ((ks*32 + lg*8) ^ xorE)]);
      #pragma unroll
      for (int ni = 0; ni < 4; ++ni)
        bfr[ni] = *reinterpret_cast<const bf16x8*>(
            &Bs[cur][(wn + ni*16 + ln)*BK + ((ks*32 + lg*8) ^ xorE)]);
      #pragma unroll
      for (int mi = 0; mi < 4; ++mi)
        #pragma unroll
        for (int ni = 0; ni < 4; ++ni)
          acc[mi][ni] = __builtin_amdgcn_mfma_f32_16x16x32_bf16(af[mi], bfr[ni], acc[mi][ni], 0, 0, 0);
    }
    __syncthreads();             // As reads done; B(t+1) prefetch drained

    if (kt < KTOT/BK - 1) {
      STAGE_A(kt + 1);           // short, mostly-L2 drain (uncovered)
      __syncthreads();           // A(t+1) landed before next compute
    }
  }
  #undef STAGE_A
  #undef STAGE_B

  int r4 = lg * 4;
  #pragma unroll
  for (int mi = 0; mi < 4; ++mi) {
    #pragma unroll
    for (int ni = 0; ni < 4; ++ni) {
      int nc = n0 + wn + ni*16 + ln;
      int c  = nc >> 10;
      int hd = nc & 1023;
      int h = hd >> 6, d = hd & 63;
      float bias = bqkv[hd*3 + c];
      float qs = (c == 0) ? QSCALE : 1.0f;   // fold softmax scale into Q
      #pragma unroll
      for (int j = 0; j < 4; ++j) {
        int m = m0 + wm + mi*16 + r4 + j;
        int n = m >> 11, t = m & 2047;
        unsigned short val = f2bf((acc[mi][ni][j] + bias) * qs);
        size_t nh = (size_t)(n*NHEADS + h);
        if (c == 0)      Qb[((nh*SEQ + t) << 6) + d] = val;
        else if (c == 1) Kb[((nh*SEQ + t) << 6) + d] = val;
        else             Vt[((nh*HDIM + d) << 11) + t] = val;
      }
    }
  }
}

// ---------------------------------------------------------------- attention
// LDS-staged flash attention (T3 2-phase pipeline), 8-wave blocks.
// Block = 8 waves = 128 q-rows, one head, full 2048-key sweep. K-tile
// [64 keys][64 d] and V-tile [64 d][64 keys] staged to LDS dbuf via
// global_load_lds (width 16), staged ONCE per 128 q-rows. Rule-21 swizzle:
// linear LDS dest + inverse-XOR source (seg ^= row&7) + XOR on ds_read.
// MFMA fragment maps (HW-validated R1/R4/R7):
//   A-frag: row=l&15, k=8*(l>>4)+j   B-frag: col=l&15, k=8*(l>>4)+j
//   C/D   : col=l&15, row=4*(l>>4)+reg
// Softmax: per-lane local max + T13 defer-max; deferred row-sum; P packed
// with v_cvt_pk_bf16_f32 (T12 recipe, RNE); P stride 176B (2-way, free).
#define PROW    88                  // P row stride, bf16 elems (176 B)
#define POFF    32768               // P regions start (after K/V staging)
#define PBYTES  2816                // 16 rows x 176 B per wave
#define OREGION 4352                // epilogue obuf: 16 x 68 f32 (reuses staging)
__launch_bounds__(512)
__global__ void attn_kernel(const unsigned short* __restrict__ Qb,
                            const unsigned short* __restrict__ Kb,
                            const unsigned short* __restrict__ Vt,
                            float* __restrict__ out) {
  __shared__ __align__(16) unsigned char smem[POFF + 8*PBYTES]; // 55296 B
  int tid = threadIdx.x;
  int w = tid >> 6, l = tid & 63;
  int ln = l & 15, lg = l >> 4;

  unsigned short* Pw  = (unsigned short*)(smem + POFF + w * PBYTES);
  float*          obw = (float*)         (smem + w * OREGION); // post-loop only

  // XCD clustering: 512 blocks, 8 XCDs -> each XCD owns 4 heads
  int fid  = blockIdx.x;
  int xcd  = fid & 7, idx = fid >> 3;       // idx 0..63
  int bh   = xcd * 4 + (idx >> 4);          // 0..31
  int qblk = idx & 15;                      // 0..15 (128 q-rows each)
  int q0   = qblk * 128 + w * 16;

  const unsigned short* Qh = Qb + (size_t)bh * SEQ * HDIM;
  const unsigned short* Kh = Kb + (size_t)bh * SEQ * HDIM;
  const unsigned short* Vh = Vt + (size_t)bh * HDIM * SEQ;

  // staging mapping: 512 threads cover one 64x64 bf16 tile in ONE call
  int srow = w*8 + (l >> 3);      // row 0..63
  int sseg = (l & 7) ^ (srow & 7);// inverse-swizzled 16B segment

  // Q B-fragments (col = q = ln), d-windows dw=0,1
  bf16x8 qf[2];
  #pragma unroll
  for (int dw = 0; dw < 2; ++dw)
    qf[dw] = *reinterpret_cast<const bf16x8*>(&Qh[(size_t)(q0 + ln)*HDIM + dw*32 + lg*8]);

  const f32x4 zero4 = {0.f, 0.f, 0.f, 0.f};
  f32x4 o[4];
  #pragma unroll
  for (int db = 0; db < 4; ++db) o[db] = zero4;
  f32x4 psum4 = zero4;
  float mrow = -INFINITY;

  // STAGE one 64-key tile: K[key][d] + V[d][key], inverse-swizzled source
  #define STAGE(BUF, KEY0)                                                    \
  do {                                                                        \
    async_copy16(smem + (BUF)*8192 + w*1024,                                  \
                 &Kh[(size_t)((KEY0) + srow)*HDIM + sseg*8]);                 \
    async_copy16(smem + 16384 + (BUF)*8192 + w*1024,                          \
                 &Vh[(size_t)srow*SEQ + (KEY0) + sseg*8]);                    \
  } while (0)

  STAGE(0, 0);
  __syncthreads();   // drains vmcnt(0): buffer 0 ready

  int xorE = (ln & 7) << 3;   // element-index XOR for swizzled ds_read

  for (int kv = 0; kv < 32; ++kv) {
    int cur  = kv & 1;
    int nkey = (kv < 31) ? (kv + 1) * 64 : kv * 64;
    STAGE(cur ^ 1, nkey);     // prefetch next tile (drained by the barrier)

    const unsigned short* Kc = (const unsigned short*)(smem + cur*8192);
    const unsigned short* Vc = (const unsigned short*)(smem + 16384 + cur*8192);

    // ---- S^T: 4 key-blocks x 2 d-windows (K A-frags from swizzled LDS)
    f32x4 s[4];
    #pragma unroll
    for (int kb = 0; kb < 4; ++kb) {
      int r = kb*16 + ln;
      bf16x8 k0 = *reinterpret_cast<const bf16x8*>(&Kc[r*HDIM + ((     lg*8) ^ xorE)]);
      bf16x8 k1 = *reinterpret_cast<const bf16x8*>(&Kc[r*HDIM + ((32 + lg*8) ^ xorE)]);
      f32x4 t0 = __builtin_amdgcn_mfma_f32_16x16x32_bf16(k0, qf[0], zero4, 0, 0, 0);
      s[kb]    = __builtin_amdgcn_mfma_f32_16x16x32_bf16(k1, qf[1], t0,    0, 0, 0);
    }

    // ---- per-lane local max over this lane's 16 keys (no cross-lane)
    f32x4 m4 = vmax4(vmax4(s[0], s[1]), vmax4(s[2], s[3]));
    float localmax = fmaxf(fmaxf(m4[0], m4[1]), fmaxf(m4[2], m4[3]));

    // ---- T13 defer-max: full reduce+rescale only when max grows (rare)
    if (!__all(localmax <= mrow + 8.f)) {
      float pm = localmax;
      pm = fmaxf(pm, __shfl_xor(pm, 16));
      pm = fmaxf(pm, __shfl_xor(pm, 32));
      float mn  = fmaxf(mrow, pm);
      float scl = __builtin_amdgcn_exp2f(mrow - mn);
      mrow = mn;
      psum4 *= scl;
      #pragma unroll
      for (int db = 0; db < 4; ++db)
        #pragma unroll
        for (int r = 0; r < 4; ++r) o[db][r] *= scl;
    }

    // ---- P = exp2(S - m); accumulate per-lane partial sums in registers
    #pragma unroll
    for (int kb = 0; kb < 4; ++kb) {
      #pragma unroll
      for (int r = 0; r < 4; ++r)
        s[kb][r] = __builtin_amdgcn_exp2f(s[kb][r] - mrow);
      psum4 += s[kb];
    }

    // ---- P -> LDS via v_cvt_pk_bf16_f32 (T12; RNE, same bits as f2bf)
    #pragma unroll
    for (int kb = 0; kb < 4; ++kb) {
      uint2 pk;
      asm("v_cvt_pk_bf16_f32 %0, %1, %2" : "=v"(pk.x) : "v"(s[kb][0]), "v"(s[kb][1]));
      asm("v_cvt_pk_bf16_f32 %0, %1, %2" : "=v"(pk.y) : "v"(s[kb][2]), "v"(s[kb][3]));
      *reinterpret_cast<uint2*>(&Pw[ln*PROW + kb*16 + 4*lg]) = pk;
    }

    // ---- PV: A = V^T frags (swizzled LDS), B = P^T from LDS
    #pragma unroll
    for (int kw = 0; kw < 2; ++kw) {
      bf16x8 pb = *reinterpret_cast<const bf16x8*>(&Pw[ln*PROW + kw*32 + lg*8]);
      #pragma unroll
      for (int db = 0; db < 4; ++db) {
        int r = db*16 + ln;
        bf16x8 vfr = *reinterpret_cast<const bf16x8*>(
            &Vc[r*64 + ((kw*32 + lg*8) ^ xorE)]);
        o[db] = __builtin_amdgcn_mfma_f32_16x16x32_bf16(vfr, pb, o[db], 0, 0, 0);
      }
    }

    __syncthreads();   // drains vmcnt(0) (next buffer staged) + LDS
  }
  #undef STAGE

  // ---- post-loop: row-sum reduce (once), normalize, transpose, store
  float ls = (psum4[0] + psum4[1]) + (psum4[2] + psum4[3]);
  ls += __shfl_xor(ls, 16);
  ls += __shfl_xor(ls, 32);
  float inv = 1.f / ls;

  #pragma unroll
  for (int db = 0; db < 4; ++db)
    #pragma unroll
    for (int r = 0; r < 4; ++r)
      obw[ln*68 + db*16 + 4*lg + r] = o[db][r] * inv;
  asm volatile("s_waitcnt lgkmcnt(0)" ::: "memory");
  int n = bh >> 4, h = bh & 15;
  #pragma unroll
  for (int p = 0; p < 4; ++p) {
    int q = p*4 + lg;
    f32x4 vv = *reinterpret_cast<const f32x4*>(&obw[q*68 + ln*4]);
    *reinterpret_cast<f32x4*>(
        &out[((size_t)(n*SEQ + q0 + q))*DMODEL + h*HDIM + ln*4]) = vv;
  }
}

// ---------------------------------------------------------------- launcher
extern "C" void kernel_launch(void* const* d_in, const int* in_sizes, int n_in,
                              void* d_out, int out_size, void* d_ws, size_t ws_size,
                              hipStream_t stream) {
  const float* x    = (const float*)d_in[0];
  // d_in[1] = mask: constant shift along query axis inside softmax -> no-op
  const float* Wq   = (const float*)d_in[2];
  const float* bq   = (const float*)d_in[3];
  float* out = (float*)d_out;

  unsigned short* xb = (unsigned short*)d_ws;                    // [4096][1024]
  unsigned short* wt = xb + (size_t)MTOT*KTOT;                   // [3072][1024]
  unsigned short* Qb = wt + (size_t)NTOT*KTOT;                   // [32][2048][64]
  unsigned short* Kb = Qb + (size_t)NB*NHEADS*SEQ*HDIM;          // [32][2048][64]
  unsigned short* Vt = Kb + (size_t)NB*NHEADS*SEQ*HDIM;          // [32][64][2048]

  convert_x_kernel<<<(MTOT*KTOT/8)/256, 256, 0, stream>>>(x, xb);
  transpose_w_kernel<<<dim3(NTOT/64, KTOT/64), 256, 0, stream>>>(Wq, wt);
  qkv_gemm_kernel<<<dim3(NBX, NBY), 256, 0, stream>>>(xb, wt, bq, Qb, Kb, Vt);
  attn_kernel<<<512, 512, 0, stream>>>(Qb, Kb, Vt, out);
}

// Round 11
// 107.985 us; speedup vs baseline: 1.2612x; 1.1546x over previous
//
#include <hip/hip_runtime.h>
#include <hip/hip_bf16.h>
#include <stdint.h>

// Sizes (fixed for this problem)
#define NHEADS 16
#define HDIM   64
#define DMODEL 1024
#define SEQ    2048
#define NB     2
#define MTOT   (NB*SEQ)     // 4096 rows of x
#define NTOT   (3*DMODEL)   // 3072 qkv cols
#define KTOT   DMODEL       // 1024

// fold (1/8)*log2(e) into Q so softmax runs in exp2 domain
#define QSCALE 0.18033688011112042f

typedef __attribute__((ext_vector_type(8)))  short          bf16x8;
typedef __attribute__((ext_vector_type(4)))  float          f32x4;
typedef __attribute__((ext_vector_type(8)))  unsigned short u16x8;

__device__ __forceinline__ unsigned short f2bf(float f) {
  unsigned u = __builtin_bit_cast(unsigned, f);
  u += 0x7fffu + ((u >> 16) & 1u);          // round-to-nearest-even
  return (unsigned short)(u >> 16);
}

__device__ __forceinline__ f32x4 vmax4(f32x4 a, f32x4 b) {
  f32x4 r;
  r[0]=fmaxf(a[0],b[0]); r[1]=fmaxf(a[1],b[1]);
  r[2]=fmaxf(a[2],b[2]); r[3]=fmaxf(a[3],b[3]);
  return r;
}

__device__ __forceinline__ void async_copy16(void* lds, const void* g) {
  __builtin_amdgcn_global_load_lds(
      (const __attribute__((address_space(1))) unsigned int*)g,
      (__attribute__((address_space(3))) unsigned int*)lds, 16, 0, 0);
}

// ---------------------------------------------------------------- convert x
__global__ void convert_x_kernel(const float* __restrict__ x,
                                 unsigned short* __restrict__ xb) {
  int i = blockIdx.x * 256 + threadIdx.x;
  const f32x4* xv = reinterpret_cast<const f32x4*>(x);
  f32x4 a = xv[2*i];
  f32x4 b = xv[2*i + 1];
  u16x8 r;
  r[0]=f2bf(a[0]); r[1]=f2bf(a[1]); r[2]=f2bf(a[2]); r[3]=f2bf(a[3]);
  r[4]=f2bf(b[0]); r[5]=f2bf(b[1]); r[6]=f2bf(b[2]); r[7]=f2bf(b[3]);
  reinterpret_cast<u16x8*>(xb)[i] = r;
}

// --------------------------------------- transpose + permute + convert W
__global__ void transpose_w_kernel(const float* __restrict__ W,
                                   unsigned short* __restrict__ Wt) {
  __shared__ float tile[64][65];
  int j0 = blockIdx.x * 64;
  int k0 = blockIdx.y * 64;
  int tid = threadIdx.x;
  int lr = tid >> 6;
  int lc = tid & 63;
  #pragma unroll
  for (int i = 0; i < 16; ++i) {
    int r = i*4 + lr;
    tile[r][lc] = W[(size_t)(k0 + r)*NTOT + j0 + lc];
  }
  __syncthreads();
  #pragma unroll
  for (int i = 0; i < 16; ++i) {
    int jr = i*4 + lr;
    int j  = j0 + jr;
    int oc = (j % 3)*DMODEL + (j / 3);
    Wt[(size_t)oc*KTOT + k0 + lc] = f2bf(tile[lc][jr]);
  }
}

// ---------------------------------------------------------------- QKV GEMM
// R11: both A and B double-buffered at BK=32 (LDS 32KB, ONE barrier/iter,
// all staging issued before compute -> covered; ~4 blocks/CU). T2 swizzle
// for 64B rows: seg' = seg ^ ((row>>1)&3) -> 2-way (free) fragment reads.
// V-epilogue (c==2 blocks, block-uniform): LDS transpose (stride 136 elems)
// -> coalesced 16B Vt stores along t (kills the 2B/4KB-stride scatter).
#define BM 128
#define BN 128
#define BK2 32
#define NBX (NTOT/BN)    // 24
#define NBY (MTOT/BM)    // 32
#define EPSTRIDE 136     // epilogue LDS row stride (elems): b64/b128 aligned
__launch_bounds__(256)
__global__ void qkv_gemm_kernel(const unsigned short* __restrict__ xb,
                                const unsigned short* __restrict__ wt,
                                const float* __restrict__ bqkv,
                                unsigned short* __restrict__ Qb,
                                unsigned short* __restrict__ Kb,
                                unsigned short* __restrict__ Vt) {
  __shared__ __align__(16) unsigned char gsm[128*EPSTRIDE*2]; // 34816 B
  unsigned short* As = (unsigned short*)gsm;            // [2][128*32] 16 KB
  unsigned short* Bs = (unsigned short*)(gsm + 16384);  // [2][128*32] 16 KB
  unsigned short* Ep = (unsigned short*)gsm;            // epilogue transpose

  int tid = threadIdx.x;
  int w = tid >> 6, l = tid & 63;
  int m0 = blockIdx.y * BM;
  int n0 = blockIdx.x * BN;
  int ln = l & 15, lg = l >> 4;
  int wm = (w >> 1) * 64;
  int wn = (w & 1) * 64;

  f32x4 acc[4][4];
  const f32x4 zero4 = {0.f, 0.f, 0.f, 0.f};
  #pragma unroll
  for (int i = 0; i < 4; ++i)
    #pragma unroll
    for (int j = 0; j < 4; ++j) acc[i][j] = zero4;

  // stage: linear LDS dest (wave-uniform base + lane*16B), pre-swizzled src
  #define STAGE2(BUF, KT)                                                     \
  do {                                                                        \
    _Pragma("unroll")                                                         \
    for (int i = 0; i < 2; ++i) {                                             \
      int row  = i*64 + w*16 + (l >> 2);                                      \
      int seg  = (l & 3) ^ ((row >> 1) & 3);                                  \
      async_copy16(gsm + (BUF)*8192 + i*4096 + w*1024,                        \
                   &xb[(size_t)(m0 + row)*KTOT + (KT)*BK2 + seg*8]);          \
      async_copy16(gsm + 16384 + (BUF)*8192 + i*4096 + w*1024,                \
                   &wt[(size_t)(n0 + row)*KTOT + (KT)*BK2 + seg*8]);          \
    }                                                                         \
  } while (0)

  STAGE2(0, 0);
  asm volatile("s_waitcnt vmcnt(0)" ::: "memory");
  __syncthreads();

  for (int kt = 0; kt < KTOT/BK2; ++kt) {
    int cur = kt & 1;
    if (kt < KTOT/BK2 - 1) STAGE2(cur ^ 1, kt + 1);   // covered by compute

    bf16x8 af[4], bfr[4];
    #pragma unroll
    for (int mi = 0; mi < 4; ++mi) {
      int ra = wm + mi*16 + ln;
      af[mi] = *reinterpret_cast<const bf16x8*>(
          &As[cur*4096 + ra*BK2 + ((lg ^ ((ra >> 1) & 3)) << 3)]);
    }
    #pragma unroll
    for (int ni = 0; ni < 4; ++ni) {
      int rb = wn + ni*16 + ln;
      bfr[ni] = *reinterpret_cast<const bf16x8*>(
          &Bs[cur*4096 + rb*BK2 + ((lg ^ ((rb >> 1) & 3)) << 3)]);
    }
    #pragma unroll
    for (int mi = 0; mi < 4; ++mi)
      #pragma unroll
      for (int ni = 0; ni < 4; ++ni)
        acc[mi][ni] = __builtin_amdgcn_mfma_f32_16x16x32_bf16(af[mi], bfr[ni], acc[mi][ni], 0, 0, 0);

    __syncthreads();   // drains prefetch (implicit vmcnt0) + LDS reads
  }
  #undef STAGE2

  int r4 = lg * 4;
  if (n0 >= 2*DMODEL) {
    // ---- V block (uniform c==2): LDS transpose -> coalesced Vt stores
    int hd0 = n0 - 2*DMODEL;
    #pragma unroll
    for (int mi = 0; mi < 4; ++mi) {
      #pragma unroll
      for (int ni = 0; ni < 4; ++ni) {
        int col = wn + ni*16 + ln;                 // hd_local
        float bias = bqkv[(hd0 + col)*3 + 2];
        int rb = wm + mi*16 + r4;                  // t_local base (mult of 4)
        ushort4 pk4;
        pk4.x = f2bf(acc[mi][ni][0] + bias);
        pk4.y = f2bf(acc[mi][ni][1] + bias);
        pk4.z = f2bf(acc[mi][ni][2] + bias);
        pk4.w = f2bf(acc[mi][ni][3] + bias);
        *reinterpret_cast<ushort4*>(&Ep[col*EPSTRIDE + rb]) = pk4;
      }
    }
    __syncthreads();
    int n = m0 >> 11, t0 = m0 & 2047;
    #pragma unroll
    for (int pass = 0; pass < 8; ++pass) {
      int hdl = pass*16 + (tid >> 4);
      int seg = tid & 15;
      bf16x8 v = *reinterpret_cast<const bf16x8*>(&Ep[hdl*EPSTRIDE + seg*8]);
      int hd = hd0 + hdl, h = hd >> 6, d = hd & 63;
      *reinterpret_cast<bf16x8*>(
          &Vt[(((size_t)(n*NHEADS + h)*HDIM + d) << 11) + t0 + seg*8]) = v;
    }
  } else {
    // ---- Q/K blocks (c==0/1): 32B-contiguous per 16-lane group
    #pragma unroll
    for (int mi = 0; mi < 4; ++mi) {
      #pragma unroll
      for (int ni = 0; ni < 4; ++ni) {
        int nc = n0 + wn + ni*16 + ln;
        int c  = nc >> 10;
        int hd = nc & 1023;
        int h = hd >> 6, d = hd & 63;
        float bias = bqkv[hd*3 + c];
        float qs = (c == 0) ? QSCALE : 1.0f;   // fold softmax scale into Q
        #pragma unroll
        for (int j = 0; j < 4; ++j) {
          int m = m0 + wm + mi*16 + r4 + j;
          int n = m >> 11, t = m & 2047;
          unsigned short val = f2bf((acc[mi][ni][j] + bias) * qs);
          size_t nh = (size_t)(n*NHEADS + h);
          if (c == 0) Qb[((nh*SEQ + t) << 6) + d] = val;
          else        Kb[((nh*SEQ + t) << 6) + d] = val;
        }
      }
    }
  }
}

// ---------------------------------------------------------------- attention
// LDS-staged flash attention (T3 2-phase pipeline), 8-wave blocks.
// Block = 8 waves = 128 q-rows, one head, full 2048-key sweep. K-tile
// [64 keys][64 d] and V-tile [64 d][64 keys] staged to LDS dbuf via
// global_load_lds (width 16), staged ONCE per 128 q-rows. Rule-21 swizzle:
// linear LDS dest + inverse-XOR source (seg ^= row&7) + XOR on ds_read.
// MFMA fragment maps (HW-validated R1/R4/R7):
//   A-frag: row=l&15, k=8*(l>>4)+j   B-frag: col=l&15, k=8*(l>>4)+j
//   C/D   : col=l&15, row=4*(l>>4)+reg
// Softmax: per-lane local max + T13 defer-max; deferred row-sum; P packed
// with v_cvt_pk_bf16_f32 (T12 recipe, RNE); P stride 176B (2-way, free).
#define PROW    88                  // P row stride, bf16 elems (176 B)
#define POFF    32768               // P regions start (after K/V staging)
#define PBYTES  2816                // 16 rows x 176 B per wave
#define OREGION 4352                // epilogue obuf: 16 x 68 f32 (reuses staging)
__launch_bounds__(512)
__global__ void attn_kernel(const unsigned short* __restrict__ Qb,
                            const unsigned short* __restrict__ Kb,
                            const unsigned short* __restrict__ Vt,
                            float* __restrict__ out) {
  __shared__ __align__(16) unsigned char smem[POFF + 8*PBYTES]; // 55296 B
  int tid = threadIdx.x;
  int w = tid >> 6, l = tid & 63;
  int ln = l & 15, lg = l >> 4;

  unsigned short* Pw  = (unsigned short*)(smem + POFF + w * PBYTES);
  float*          obw = (float*)         (smem + w * OREGION); // post-loop only

  // XCD clustering: 512 blocks, 8 XCDs -> each XCD owns 4 heads
  int fid  = blockIdx.x;
  int xcd  = fid & 7, idx = fid >> 3;       // idx 0..63
  int bh   = xcd * 4 + (idx >> 4);          // 0..31
  int qblk = idx & 15;                      // 0..15 (128 q-rows each)
  int q0   = qblk * 128 + w * 16;

  const unsigned short* Qh = Qb + (size_t)bh * SEQ * HDIM;
  const unsigned short* Kh = Kb + (size_t)bh * SEQ * HDIM;
  const unsigned short* Vh = Vt + (size_t)bh * HDIM * SEQ;

  // staging mapping: 512 threads cover one 64x64 bf16 tile in ONE call
  int srow = w*8 + (l >> 3);      // row 0..63
  int sseg = (l & 7) ^ (srow & 7);// inverse-swizzled 16B segment

  // Q B-fragments (col = q = ln), d-windows dw=0,1
  bf16x8 qf[2];
  #pragma unroll
  for (int dw = 0; dw < 2; ++dw)
    qf[dw] = *reinterpret_cast<const bf16x8*>(&Qh[(size_t)(q0 + ln)*HDIM + dw*32 + lg*8]);

  const f32x4 zero4 = {0.f, 0.f, 0.f, 0.f};
  f32x4 o[4];
  #pragma unroll
  for (int db = 0; db < 4; ++db) o[db] = zero4;
  f32x4 psum4 = zero4;
  float mrow = -INFINITY;

  // STAGE one 64-key tile: K[key][d] + V[d][key], inverse-swizzled source
  #define STAGE(BUF, KEY0)                                                    \
  do {                                                                        \
    async_copy16(smem + (BUF)*8192 + w*1024,                                  \
                 &Kh[(size_t)((KEY0) + srow)*HDIM + sseg*8]);                 \
    async_copy16(smem + 16384 + (BUF)*8192 + w*1024,                          \
                 &Vh[(size_t)srow*SEQ + (KEY0) + sseg*8]);                    \
  } while (0)

  STAGE(0, 0);
  __syncthreads();   // drains vmcnt(0): buffer 0 ready

  int xorE = (ln & 7) << 3;   // element-index XOR for swizzled ds_read

  for (int kv = 0; kv < 32; ++kv) {
    int cur  = kv & 1;
    int nkey = (kv < 31) ? (kv + 1) * 64 : kv * 64;
    STAGE(cur ^ 1, nkey);     // prefetch next tile (drained by the barrier)

    const unsigned short* Kc = (const unsigned short*)(smem + cur*8192);
    const unsigned short* Vc = (const unsigned short*)(smem + 16384 + cur*8192);

    // ---- S^T: 4 key-blocks x 2 d-windows (K A-frags from swizzled LDS)
    f32x4 s[4];
    #pragma unroll
    for (int kb = 0; kb < 4; ++kb) {
      int r = kb*16 + ln;
      bf16x8 k0 = *reinterpret_cast<const bf16x8*>(&Kc[r*HDIM + ((     lg*8) ^ xorE)]);
      bf16x8 k1 = *reinterpret_cast<const bf16x8*>(&Kc[r*HDIM + ((32 + lg*8) ^ xorE)]);
      f32x4 t0 = __builtin_amdgcn_mfma_f32_16x16x32_bf16(k0, qf[0], zero4, 0, 0, 0);
      s[kb]    = __builtin_amdgcn_mfma_f32_16x16x32_bf16(k1, qf[1], t0,    0, 0, 0);
    }

    // ---- per-lane local max over this lane's 16 keys (no cross-lane)
    f32x4 m4 = vmax4(vmax4(s[0], s[1]), vmax4(s[2], s[3]));
    float localmax = fmaxf(fmaxf(m4[0], m4[1]), fmaxf(m4[2], m4[3]));

    // ---- T13 defer-max: full reduce+rescale only when max grows (rare)
    if (!__all(localmax <= mrow + 8.f)) {
      float pm = localmax;
      pm = fmaxf(pm, __shfl_xor(pm, 16));
      pm = fmaxf(pm, __shfl_xor(pm, 32));
      float mn  = fmaxf(mrow, pm);
      float scl = __builtin_amdgcn_exp2f(mrow - mn);
      mrow = mn;
      psum4 *= scl;
      #pragma unroll
      for (int db = 0; db < 4; ++db)
        #pragma unroll
        for (int r = 0; r < 4; ++r) o[db][r] *= scl;
    }

    // ---- P = exp2(S - m); accumulate per-lane partial sums in registers
    #pragma unroll
    for (int kb = 0; kb < 4; ++kb) {
      #pragma unroll
      for (int r = 0; r < 4; ++r)
        s[kb][r] = __builtin_amdgcn_exp2f(s[kb][r] - mrow);
      psum4 += s[kb];
    }

    // ---- P -> LDS via v_cvt_pk_bf16_f32 (T12; RNE, same bits as f2bf)
    #pragma unroll
    for (int kb = 0; kb < 4; ++kb) {
      uint2 pk;
      asm("v_cvt_pk_bf16_f32 %0, %1, %2" : "=v"(pk.x) : "v"(s[kb][0]), "v"(s[kb][1]));
      asm("v_cvt_pk_bf16_f32 %0, %1, %2" : "=v"(pk.y) : "v"(s[kb][2]), "v"(s[kb][3]));
      *reinterpret_cast<uint2*>(&Pw[ln*PROW + kb*16 + 4*lg]) = pk;
    }

    // ---- PV: A = V^T frags (swizzled LDS), B = P^T from LDS
    #pragma unroll
    for (int kw = 0; kw < 2; ++kw) {
      bf16x8 pb = *reinterpret_cast<const bf16x8*>(&Pw[ln*PROW + kw*32 + lg*8]);
      #pragma unroll
      for (int db = 0; db < 4; ++db) {
        int r = db*16 + ln;
        bf16x8 vfr = *reinterpret_cast<const bf16x8*>(
            &Vc[r*64 + ((kw*32 + lg*8) ^ xorE)]);
        o[db] = __builtin_amdgcn_mfma_f32_16x16x32_bf16(vfr, pb, o[db], 0, 0, 0);
      }
    }

    __syncthreads();   // drains vmcnt(0) (next buffer staged) + LDS
  }
  #undef STAGE

  // ---- post-loop: row-sum reduce (once), normalize, transpose, store
  float ls = (psum4[0] + psum4[1]) + (psum4[2] + psum4[3]);
  ls += __shfl_xor(ls, 16);
  ls += __shfl_xor(ls, 32);
  float inv = 1.f / ls;

  #pragma unroll
  for (int db = 0; db < 4; ++db)
    #pragma unroll
    for (int r = 0; r < 4; ++r)
      obw[ln*68 + db*16 + 4*lg + r] = o[db][r] * inv;
  asm volatile("s_waitcnt lgkmcnt(0)" ::: "memory");
  int n = bh >> 4, h = bh & 15;
  #pragma unroll
  for (int p = 0; p < 4; ++p) {
    int q = p*4 + lg;
    f32x4 vv = *reinterpret_cast<const f32x4*>(&obw[q*68 + ln*4]);
    *reinterpret_cast<f32x4*>(
        &out[((size_t)(n*SEQ + q0 + q))*DMODEL + h*HDIM + ln*4]) = vv;
  }
}

// ---------------------------------------------------------------- launcher
extern "C" void kernel_launch(void* const* d_in, const int* in_sizes, int n_in,
                              void* d_out, int out_size, void* d_ws, size_t ws_size,
                              hipStream_t stream) {
  const float* x    = (const float*)d_in[0];
  // d_in[1] = mask: constant shift along query axis inside softmax -> no-op
  const float* Wq   = (const float*)d_in[2];
  const float* bq   = (const float*)d_in[3];
  float* out = (float*)d_out;

  unsigned short* xb = (unsigned short*)d_ws;                    // [4096][1024]
  unsigned short* wt = xb + (size_t)MTOT*KTOT;                   // [3072][1024]
  unsigned short* Qb = wt + (size_t)NTOT*KTOT;                   // [32][2048][64]
  unsigned short* Kb = Qb + (size_t)NB*NHEADS*SEQ*HDIM;          // [32][2048][64]
  unsigned short* Vt = Kb + (size_t)NB*NHEADS*SEQ*HDIM;          // [32][64][2048]

  convert_x_kernel<<<(MTOT*KTOT/8)/256, 256, 0, stream>>>(x, xb);
  transpose_w_kernel<<<dim3(NTOT/64, KTOT/64), 256, 0, stream>>>(Wq, wt);
  qkv_gemm_kernel<<<dim3(NBX, NBY), 256, 0, stream>>>(xb, wt, bq, Qb, Kb, Vt);
  attn_kernel<<<512, 512, 0, stream>>>(Qb, Kb, Vt, out);
}

// Round 12
// 107.422 us; speedup vs baseline: 1.2678x; 1.0052x over previous
//
#include <hip/hip_runtime.h>
#include <hip/hip_bf16.h>
#include <stdint.h>

// Sizes (fixed for this problem)
#define NHEADS 16
#define HDIM   64
#define DMODEL 1024
#define SEQ    2048
#define NB     2
#define MTOT   (NB*SEQ)     // 4096 rows of x
#define NTOT   (3*DMODEL)   // 3072 qkv cols
#define KTOT   DMODEL       // 1024

// fold (1/8)*log2(e) into Q so softmax runs in exp2 domain
#define QSCALE 0.18033688011112042f

typedef __attribute__((ext_vector_type(8)))  short          bf16x8;
typedef __attribute__((ext_vector_type(4)))  float          f32x4;
typedef __attribute__((ext_vector_type(8)))  unsigned short u16x8;

__device__ __forceinline__ unsigned short f2bf(float f) {
  unsigned u = __builtin_bit_cast(unsigned, f);
  u += 0x7fffu + ((u >> 16) & 1u);          // round-to-nearest-even
  return (unsigned short)(u >> 16);
}

__device__ __forceinline__ f32x4 vmax4(f32x4 a, f32x4 b) {
  f32x4 r;
  r[0]=fmaxf(a[0],b[0]); r[1]=fmaxf(a[1],b[1]);
  r[2]=fmaxf(a[2],b[2]); r[3]=fmaxf(a[3],b[3]);
  return r;
}

__device__ __forceinline__ void async_copy16(void* lds, const void* g) {
  __builtin_amdgcn_global_load_lds(
      (const __attribute__((address_space(1))) unsigned int*)g,
      (__attribute__((address_space(3))) unsigned int*)lds, 16, 0, 0);
}

// ---------------------------------------------------------------- convert x
__global__ void convert_x_kernel(const float* __restrict__ x,
                                 unsigned short* __restrict__ xb) {
  int i = blockIdx.x * 256 + threadIdx.x;
  const f32x4* xv = reinterpret_cast<const f32x4*>(x);
  f32x4 a = xv[2*i];
  f32x4 b = xv[2*i + 1];
  u16x8 r;
  r[0]=f2bf(a[0]); r[1]=f2bf(a[1]); r[2]=f2bf(a[2]); r[3]=f2bf(a[3]);
  r[4]=f2bf(b[0]); r[5]=f2bf(b[1]); r[6]=f2bf(b[2]); r[7]=f2bf(b[3]);
  reinterpret_cast<u16x8*>(xb)[i] = r;
}

// --------------------------------------- transpose + permute + convert W
__global__ void transpose_w_kernel(const float* __restrict__ W,
                                   unsigned short* __restrict__ Wt) {
  __shared__ float tile[64][65];
  int j0 = blockIdx.x * 64;
  int k0 = blockIdx.y * 64;
  int tid = threadIdx.x;
  int lr = tid >> 6;
  int lc = tid & 63;
  #pragma unroll
  for (int i = 0; i < 16; ++i) {
    int r = i*4 + lr;
    tile[r][lc] = W[(size_t)(k0 + r)*NTOT + j0 + lc];
  }
  __syncthreads();
  #pragma unroll
  for (int i = 0; i < 16; ++i) {
    int jr = i*4 + lr;
    int j  = j0 + jr;
    int oc = (j % 3)*DMODEL + (j / 3);
    Wt[(size_t)oc*KTOT + k0 + lc] = f2bf(tile[lc][jr]);
  }
}

// ---------------------------------------------------------------- QKV GEMM
// R11 structure (kept): A+B double-buffered at BK=32, one barrier/iter,
// T2 swizzle (seg ^ ((row>>1)&3)); V-epilogue LDS transpose.
#define BM 128
#define BN 128
#define BK2 32
#define NBX (NTOT/BN)    // 24
#define NBY (MTOT/BM)    // 32
#define EPSTRIDE 136     // epilogue LDS row stride (elems): b64/b128 aligned
__launch_bounds__(256)
__global__ void qkv_gemm_kernel(const unsigned short* __restrict__ xb,
                                const unsigned short* __restrict__ wt,
                                const float* __restrict__ bqkv,
                                unsigned short* __restrict__ Qb,
                                unsigned short* __restrict__ Kb,
                                unsigned short* __restrict__ Vt) {
  __shared__ __align__(16) unsigned char gsm[128*EPSTRIDE*2]; // 34816 B
  unsigned short* As = (unsigned short*)gsm;            // [2][128*32] 16 KB
  unsigned short* Bs = (unsigned short*)(gsm + 16384);  // [2][128*32] 16 KB
  unsigned short* Ep = (unsigned short*)gsm;            // epilogue transpose

  int tid = threadIdx.x;
  int w = tid >> 6, l = tid & 63;
  int m0 = blockIdx.y * BM;
  int n0 = blockIdx.x * BN;
  int ln = l & 15, lg = l >> 4;
  int wm = (w >> 1) * 64;
  int wn = (w & 1) * 64;

  f32x4 acc[4][4];
  const f32x4 zero4 = {0.f, 0.f, 0.f, 0.f};
  #pragma unroll
  for (int i = 0; i < 4; ++i)
    #pragma unroll
    for (int j = 0; j < 4; ++j) acc[i][j] = zero4;

  // stage: linear LDS dest (wave-uniform base + lane*16B), pre-swizzled src
  #define STAGE2(BUF, KT)                                                     \
  do {                                                                        \
    _Pragma("unroll")                                                         \
    for (int i = 0; i < 2; ++i) {                                             \
      int row  = i*64 + w*16 + (l >> 2);                                      \
      int seg  = (l & 3) ^ ((row >> 1) & 3);                                  \
      async_copy16(gsm + (BUF)*8192 + i*4096 + w*1024,                        \
                   &xb[(size_t)(m0 + row)*KTOT + (KT)*BK2 + seg*8]);          \
      async_copy16(gsm + 16384 + (BUF)*8192 + i*4096 + w*1024,                \
                   &wt[(size_t)(n0 + row)*KTOT + (KT)*BK2 + seg*8]);          \
    }                                                                         \
  } while (0)

  STAGE2(0, 0);
  asm volatile("s_waitcnt vmcnt(0)" ::: "memory");
  __syncthreads();

  for (int kt = 0; kt < KTOT/BK2; ++kt) {
    int cur = kt & 1;
    if (kt < KTOT/BK2 - 1) STAGE2(cur ^ 1, kt + 1);   // covered by compute

    bf16x8 af[4], bfr[4];
    #pragma unroll
    for (int mi = 0; mi < 4; ++mi) {
      int ra = wm + mi*16 + ln;
      af[mi] = *reinterpret_cast<const bf16x8*>(
          &As[cur*4096 + ra*BK2 + ((lg ^ ((ra >> 1) & 3)) << 3)]);
    }
    #pragma unroll
    for (int ni = 0; ni < 4; ++ni) {
      int rb = wn + ni*16 + ln;
      bfr[ni] = *reinterpret_cast<const bf16x8*>(
          &Bs[cur*4096 + rb*BK2 + ((lg ^ ((rb >> 1) & 3)) << 3)]);
    }
    #pragma unroll
    for (int mi = 0; mi < 4; ++mi)
      #pragma unroll
      for (int ni = 0; ni < 4; ++ni)
        acc[mi][ni] = __builtin_amdgcn_mfma_f32_16x16x32_bf16(af[mi], bfr[ni], acc[mi][ni], 0, 0, 0);

    __syncthreads();   // drains prefetch (implicit vmcnt0) + LDS reads
  }
  #undef STAGE2

  int r4 = lg * 4;
  if (n0 >= 2*DMODEL) {
    // ---- V block (uniform c==2): LDS transpose -> coalesced Vt stores
    int hd0 = n0 - 2*DMODEL;
    #pragma unroll
    for (int mi = 0; mi < 4; ++mi) {
      #pragma unroll
      for (int ni = 0; ni < 4; ++ni) {
        int col = wn + ni*16 + ln;                 // hd_local
        float bias = bqkv[(hd0 + col)*3 + 2];
        int rb = wm + mi*16 + r4;                  // t_local base (mult of 4)
        ushort4 pk4;
        pk4.x = f2bf(acc[mi][ni][0] + bias);
        pk4.y = f2bf(acc[mi][ni][1] + bias);
        pk4.z = f2bf(acc[mi][ni][2] + bias);
        pk4.w = f2bf(acc[mi][ni][3] + bias);
        *reinterpret_cast<ushort4*>(&Ep[col*EPSTRIDE + rb]) = pk4;
      }
    }
    __syncthreads();
    int n = m0 >> 11, t0 = m0 & 2047;
    #pragma unroll
    for (int pass = 0; pass < 8; ++pass) {
      int hdl = pass*16 + (tid >> 4);
      int seg = tid & 15;
      bf16x8 v = *reinterpret_cast<const bf16x8*>(&Ep[hdl*EPSTRIDE + seg*8]);
      int hd = hd0 + hdl, h = hd >> 6, d = hd & 63;
      *reinterpret_cast<bf16x8*>(
          &Vt[(((size_t)(n*NHEADS + h)*HDIM + d) << 11) + t0 + seg*8]) = v;
    }
  } else {
    // ---- Q/K blocks (c==0/1): 32B-contiguous per 16-lane group
    #pragma unroll
    for (int mi = 0; mi < 4; ++mi) {
      #pragma unroll
      for (int ni = 0; ni < 4; ++ni) {
        int nc = n0 + wn + ni*16 + ln;
        int c  = nc >> 10;
        int hd = nc & 1023;
        int h = hd >> 6, d = hd & 63;
        float bias = bqkv[hd*3 + c];
        float qs = (c == 0) ? QSCALE : 1.0f;   // fold softmax scale into Q
        #pragma unroll
        for (int j = 0; j < 4; ++j) {
          int m = m0 + wm + mi*16 + r4 + j;
          int n = m >> 11, t = m & 2047;
          unsigned short val = f2bf((acc[mi][ni][j] + bias) * qs);
          size_t nh = (size_t)(n*NHEADS + h);
          if (c == 0) Qb[((nh*SEQ + t) << 6) + d] = val;
          else        Kb[((nh*SEQ + t) << 6) + d] = val;
        }
      }
    }
  }
}

// ---------------------------------------------------------------- attention
// R12: T4 counted-vmcnt 3-buffer pipeline (prefetch distance 2). Per tile:
//   STAGE(t+2) -> compute(t) -> s_waitcnt vmcnt(2) -> s_barrier
// vmcnt(2) releases once tile t+1 (issued one full iteration ago) landed;
// tile t+2's 2 loads stay in flight ACROSS the barrier (never vmcnt(0)).
// Ledger: write buf (t+2)%3 vs read buf t%3 disjoint; WAR on (t+2)%3: last
// read at iter t-1, consumed (lgkmcnt before MFMA) before that barrier.
// Everything else identical to R11 (validated): fragment maps, swizzle,
// defer-max softmax, cvt_pk P-pack, P stride 176B, epilogue transpose.
#define PROW    88                  // P row stride, bf16 elems (176 B)
#define POFF    49152               // P regions start (after 3 staging bufs)
#define PBYTES  2816                // 16 rows x 176 B per wave
#define OREGION 4352                // epilogue obuf: 16 x 68 f32 (reuses staging)
__launch_bounds__(512)
__global__ void attn_kernel(const unsigned short* __restrict__ Qb,
                            const unsigned short* __restrict__ Kb,
                            const unsigned short* __restrict__ Vt,
                            float* __restrict__ out) {
  __shared__ __align__(16) unsigned char smem[POFF + 8*PBYTES]; // 71680 B
  int tid = threadIdx.x;
  int w = tid >> 6, l = tid & 63;
  int ln = l & 15, lg = l >> 4;

  unsigned short* Pw  = (unsigned short*)(smem + POFF + w * PBYTES);
  float*          obw = (float*)         (smem + w * OREGION); // post-loop only

  // XCD clustering: 512 blocks, 8 XCDs -> each XCD owns 4 heads
  int fid  = blockIdx.x;
  int xcd  = fid & 7, idx = fid >> 3;       // idx 0..63
  int bh   = xcd * 4 + (idx >> 4);          // 0..31
  int qblk = idx & 15;                      // 0..15 (128 q-rows each)
  int q0   = qblk * 128 + w * 16;

  const unsigned short* Qh = Qb + (size_t)bh * SEQ * HDIM;
  const unsigned short* Kh = Kb + (size_t)bh * SEQ * HDIM;
  const unsigned short* Vh = Vt + (size_t)bh * HDIM * SEQ;

  // staging mapping: 512 threads cover one 64x64 bf16 tile in ONE call
  int srow = w*8 + (l >> 3);      // row 0..63
  int sseg = (l & 7) ^ (srow & 7);// inverse-swizzled 16B segment

  // Q B-fragments (col = q = ln), d-windows dw=0,1
  bf16x8 qf[2];
  #pragma unroll
  for (int dw = 0; dw < 2; ++dw)
    qf[dw] = *reinterpret_cast<const bf16x8*>(&Qh[(size_t)(q0 + ln)*HDIM + dw*32 + lg*8]);

  const f32x4 zero4 = {0.f, 0.f, 0.f, 0.f};
  f32x4 o[4];
  #pragma unroll
  for (int db = 0; db < 4; ++db) o[db] = zero4;
  f32x4 psum4 = zero4;
  float mrow = -INFINITY;

  // STAGE one 64-key tile into buffer BUF: K[key][d] + V[d][key]
  #define STAGE(BUF, KEY0)                                                    \
  do {                                                                        \
    async_copy16(smem + (BUF)*16384 + w*1024,                                 \
                 &Kh[(size_t)((KEY0) + srow)*HDIM + sseg*8]);                 \
    async_copy16(smem + (BUF)*16384 + 8192 + w*1024,                          \
                 &Vh[(size_t)srow*SEQ + (KEY0) + sseg*8]);                    \
  } while (0)

  STAGE(0, 0);
  STAGE(1, 64);
  asm volatile("s_waitcnt vmcnt(2)" ::: "memory");   // tile 0 landed
  __builtin_amdgcn_s_barrier();
  asm volatile("" ::: "memory");

  int xorE = (ln & 7) << 3;   // element-index XOR for swizzled ds_read
  int cur = 0, nxt2 = 2;      // buffer of tile kv, buffer for tile kv+2

  for (int kv = 0; kv < 32; ++kv) {
    if (kv < 30) STAGE(nxt2, (kv + 2) * 64);   // in flight across barrier

    const unsigned short* Kc = (const unsigned short*)(smem + cur*16384);
    const unsigned short* Vc = (const unsigned short*)(smem + cur*16384 + 8192);

    // ---- S^T: 4 key-blocks x 2 d-windows (K A-frags from swizzled LDS)
    f32x4 s[4];
    #pragma unroll
    for (int kb = 0; kb < 4; ++kb) {
      int r = kb*16 + ln;
      bf16x8 k0 = *reinterpret_cast<const bf16x8*>(&Kc[r*HDIM + ((     lg*8) ^ xorE)]);
      bf16x8 k1 = *reinterpret_cast<const bf16x8*>(&Kc[r*HDIM + ((32 + lg*8) ^ xorE)]);
      f32x4 t0 = __builtin_amdgcn_mfma_f32_16x16x32_bf16(k0, qf[0], zero4, 0, 0, 0);
      s[kb]    = __builtin_amdgcn_mfma_f32_16x16x32_bf16(k1, qf[1], t0,    0, 0, 0);
    }

    // ---- per-lane local max over this lane's 16 keys (no cross-lane)
    f32x4 m4 = vmax4(vmax4(s[0], s[1]), vmax4(s[2], s[3]));
    float localmax = fmaxf(fmaxf(m4[0], m4[1]), fmaxf(m4[2], m4[3]));

    // ---- T13 defer-max: full reduce+rescale only when max grows (rare)
    if (!__all(localmax <= mrow + 8.f)) {
      float pm = localmax;
      pm = fmaxf(pm, __shfl_xor(pm, 16));
      pm = fmaxf(pm, __shfl_xor(pm, 32));
      float mn  = fmaxf(mrow, pm);
      float scl = __builtin_amdgcn_exp2f(mrow - mn);
      mrow = mn;
      psum4 *= scl;
      #pragma unroll
      for (int db = 0; db < 4; ++db)
        #pragma unroll
        for (int r = 0; r < 4; ++r) o[db][r] *= scl;
    }

    // ---- P = exp2(S - m); accumulate per-lane partial sums in registers
    #pragma unroll
    for (int kb = 0; kb < 4; ++kb) {
      #pragma unroll
      for (int r = 0; r < 4; ++r)
        s[kb][r] = __builtin_amdgcn_exp2f(s[kb][r] - mrow);
      psum4 += s[kb];
    }

    // ---- P -> LDS via v_cvt_pk_bf16_f32 (T12; RNE, same bits as f2bf)
    #pragma unroll
    for (int kb = 0; kb < 4; ++kb) {
      uint2 pk;
      asm("v_cvt_pk_bf16_f32 %0, %1, %2" : "=v"(pk.x) : "v"(s[kb][0]), "v"(s[kb][1]));
      asm("v_cvt_pk_bf16_f32 %0, %1, %2" : "=v"(pk.y) : "v"(s[kb][2]), "v"(s[kb][3]));
      *reinterpret_cast<uint2*>(&Pw[ln*PROW + kb*16 + 4*lg]) = pk;
    }

    // ---- PV: A = V^T frags (swizzled LDS), B = P^T from LDS
    #pragma unroll
    for (int kw = 0; kw < 2; ++kw) {
      bf16x8 pb = *reinterpret_cast<const bf16x8*>(&Pw[ln*PROW + kw*32 + lg*8]);
      #pragma unroll
      for (int db = 0; db < 4; ++db) {
        int r = db*16 + ln;
        bf16x8 vfr = *reinterpret_cast<const bf16x8*>(
            &Vc[r*64 + ((kw*32 + lg*8) ^ xorE)]);
        o[db] = __builtin_amdgcn_mfma_f32_16x16x32_bf16(vfr, pb, o[db], 0, 0, 0);
      }
    }

    // ---- counted wait: tile kv+1 landed; kv+2 stays in flight
    if (kv < 30) asm volatile("s_waitcnt vmcnt(2)" ::: "memory");
    else         asm volatile("s_waitcnt vmcnt(0)" ::: "memory");
    __builtin_amdgcn_s_barrier();
    asm volatile("" ::: "memory");

    cur  = (cur  == 2) ? 0 : cur  + 1;
    nxt2 = (nxt2 == 2) ? 0 : nxt2 + 1;
  }
  #undef STAGE

  // ---- post-loop: row-sum reduce (once), normalize, transpose, store
  float ls = (psum4[0] + psum4[1]) + (psum4[2] + psum4[3]);
  ls += __shfl_xor(ls, 16);
  ls += __shfl_xor(ls, 32);
  float inv = 1.f / ls;

  #pragma unroll
  for (int db = 0; db < 4; ++db)
    #pragma unroll
    for (int r = 0; r < 4; ++r)
      obw[ln*68 + db*16 + 4*lg + r] = o[db][r] * inv;
  asm volatile("s_waitcnt lgkmcnt(0)" ::: "memory");
  int n = bh >> 4, h = bh & 15;
  #pragma unroll
  for (int p = 0; p < 4; ++p) {
    int q = p*4 + lg;
    f32x4 vv = *reinterpret_cast<const f32x4*>(&obw[q*68 + ln*4]);
    *reinterpret_cast<f32x4*>(
        &out[((size_t)(n*SEQ + q0 + q))*DMODEL + h*HDIM + ln*4]) = vv;
  }
}

// ---------------------------------------------------------------- launcher
extern "C" void kernel_launch(void* const* d_in, const int* in_sizes, int n_in,
                              void* d_out, int out_size, void* d_ws, size_t ws_size,
                              hipStream_t stream) {
  const float* x    = (const float*)d_in[0];
  // d_in[1] = mask: constant shift along query axis inside softmax -> no-op
  const float* Wq   = (const float*)d_in[2];
  const float* bq   = (const float*)d_in[3];
  float* out = (float*)d_out;

  unsigned short* xb = (unsigned short*)d_ws;                    // [4096][1024]
  unsigned short* wt = xb + (size_t)MTOT*KTOT;                   // [3072][1024]
  unsigned short* Qb = wt + (size_t)NTOT*KTOT;                   // [32][2048][64]
  unsigned short* Kb = Qb + (size_t)NB*NHEADS*SEQ*HDIM;          // [32][2048][64]
  unsigned short* Vt = Kb + (size_t)NB*NHEADS*SEQ*HDIM;          // [32][64][2048]

  convert_x_kernel<<<(MTOT*KTOT/8)/256, 256, 0, stream>>>(x, xb);
  transpose_w_kernel<<<dim3(NTOT/64, KTOT/64), 256, 0, stream>>>(Wq, wt);
  qkv_gemm_kernel<<<dim3(NBX, NBY), 256, 0, stream>>>(xb, wt, bq, Qb, Kb, Vt);
  attn_kernel<<<512, 512, 0, stream>>>(Qb, Kb, Vt, out);
}

// Round 13
// 106.972 us; speedup vs baseline: 1.2731x; 1.0042x over previous
//
#include <hip/hip_runtime.h>
#include <hip/hip_bf16.h>
#include <stdint.h>

// Sizes (fixed for this problem)
#define NHEADS 16
#define HDIM   64
#define DMODEL 1024
#define SEQ    2048
#define NB     2
#define MTOT   (NB*SEQ)     // 4096 rows of x
#define NTOT   (3*DMODEL)   // 3072 qkv cols
#define KTOT   DMODEL       // 1024

// fold (1/8)*log2(e) into Q so softmax runs in exp2 domain
#define QSCALE 0.18033688011112042f

typedef __attribute__((ext_vector_type(8)))  short          bf16x8;
typedef __attribute__((ext_vector_type(4)))  float          f32x4;
typedef __attribute__((ext_vector_type(8)))  unsigned short u16x8;

__device__ __forceinline__ unsigned short f2bf(float f) {
  unsigned u = __builtin_bit_cast(unsigned, f);
  u += 0x7fffu + ((u >> 16) & 1u);          // round-to-nearest-even
  return (unsigned short)(u >> 16);
}

__device__ __forceinline__ f32x4 vmax4(f32x4 a, f32x4 b) {
  f32x4 r;
  r[0]=fmaxf(a[0],b[0]); r[1]=fmaxf(a[1],b[1]);
  r[2]=fmaxf(a[2],b[2]); r[3]=fmaxf(a[3],b[3]);
  return r;
}

__device__ __forceinline__ void async_copy16(void* lds, const void* g) {
  __builtin_amdgcn_global_load_lds(
      (const __attribute__((address_space(1))) unsigned int*)g,
      (__attribute__((address_space(3))) unsigned int*)lds, 16, 0, 0);
}

// ---------------------------------------------------------------- convert x
__global__ void convert_x_kernel(const float* __restrict__ x,
                                 unsigned short* __restrict__ xb) {
  int i = blockIdx.x * 256 + threadIdx.x;
  const f32x4* xv = reinterpret_cast<const f32x4*>(x);
  f32x4 a = xv[2*i];
  f32x4 b = xv[2*i + 1];
  u16x8 r;
  r[0]=f2bf(a[0]); r[1]=f2bf(a[1]); r[2]=f2bf(a[2]); r[3]=f2bf(a[3]);
  r[4]=f2bf(b[0]); r[5]=f2bf(b[1]); r[6]=f2bf(b[2]); r[7]=f2bf(b[3]);
  reinterpret_cast<u16x8*>(xb)[i] = r;
}

// --------------------------------------- transpose + permute + convert W
__global__ void transpose_w_kernel(const float* __restrict__ W,
                                   unsigned short* __restrict__ Wt) {
  __shared__ float tile[64][65];
  int j0 = blockIdx.x * 64;
  int k0 = blockIdx.y * 64;
  int tid = threadIdx.x;
  int lr = tid >> 6;
  int lc = tid & 63;
  #pragma unroll
  for (int i = 0; i < 16; ++i) {
    int r = i*4 + lr;
    tile[r][lc] = W[(size_t)(k0 + r)*NTOT + j0 + lc];
  }
  __syncthreads();
  #pragma unroll
  for (int i = 0; i < 16; ++i) {
    int jr = i*4 + lr;
    int j  = j0 + jr;
    int oc = (j % 3)*DMODEL + (j / 3);
    Wt[(size_t)oc*KTOT + k0 + lc] = f2bf(tile[lc][jr]);
  }
}

// ---------------------------------------------------------------- QKV GEMM
// R11 structure (kept): A+B double-buffered at BK=32, one barrier/iter,
// T2 swizzle (seg ^ ((row>>1)&3)); V-epilogue LDS transpose.
#define BM 128
#define BN 128
#define BK2 32
#define NBX (NTOT/BN)    // 24
#define NBY (MTOT/BM)    // 32
#define EPSTRIDE 136     // epilogue LDS row stride (elems): b64/b128 aligned
__launch_bounds__(256)
__global__ void qkv_gemm_kernel(const unsigned short* __restrict__ xb,
                                const unsigned short* __restrict__ wt,
                                const float* __restrict__ bqkv,
                                unsigned short* __restrict__ Qb,
                                unsigned short* __restrict__ Kb,
                                unsigned short* __restrict__ Vt) {
  __shared__ __align__(16) unsigned char gsm[128*EPSTRIDE*2]; // 34816 B
  unsigned short* As = (unsigned short*)gsm;            // [2][128*32] 16 KB
  unsigned short* Bs = (unsigned short*)(gsm + 16384);  // [2][128*32] 16 KB
  unsigned short* Ep = (unsigned short*)gsm;            // epilogue transpose

  int tid = threadIdx.x;
  int w = tid >> 6, l = tid & 63;
  int m0 = blockIdx.y * BM;
  int n0 = blockIdx.x * BN;
  int ln = l & 15, lg = l >> 4;
  int wm = (w >> 1) * 64;
  int wn = (w & 1) * 64;

  f32x4 acc[4][4];
  const f32x4 zero4 = {0.f, 0.f, 0.f, 0.f};
  #pragma unroll
  for (int i = 0; i < 4; ++i)
    #pragma unroll
    for (int j = 0; j < 4; ++j) acc[i][j] = zero4;

  // stage: linear LDS dest (wave-uniform base + lane*16B), pre-swizzled src
  #define STAGE2(BUF, KT)                                                     \
  do {                                                                        \
    _Pragma("unroll")                                                         \
    for (int i = 0; i < 2; ++i) {                                             \
      int row  = i*64 + w*16 + (l >> 2);                                      \
      int seg  = (l & 3) ^ ((row >> 1) & 3);                                  \
      async_copy16(gsm + (BUF)*8192 + i*4096 + w*1024,                        \
                   &xb[(size_t)(m0 + row)*KTOT + (KT)*BK2 + seg*8]);          \
      async_copy16(gsm + 16384 + (BUF)*8192 + i*4096 + w*1024,                \
                   &wt[(size_t)(n0 + row)*KTOT + (KT)*BK2 + seg*8]);          \
    }                                                                         \
  } while (0)

  STAGE2(0, 0);
  asm volatile("s_waitcnt vmcnt(0)" ::: "memory");
  __syncthreads();

  for (int kt = 0; kt < KTOT/BK2; ++kt) {
    int cur = kt & 1;
    if (kt < KTOT/BK2 - 1) STAGE2(cur ^ 1, kt + 1);   // covered by compute

    bf16x8 af[4], bfr[4];
    #pragma unroll
    for (int mi = 0; mi < 4; ++mi) {
      int ra = wm + mi*16 + ln;
      af[mi] = *reinterpret_cast<const bf16x8*>(
          &As[cur*4096 + ra*BK2 + ((lg ^ ((ra >> 1) & 3)) << 3)]);
    }
    #pragma unroll
    for (int ni = 0; ni < 4; ++ni) {
      int rb = wn + ni*16 + ln;
      bfr[ni] = *reinterpret_cast<const bf16x8*>(
          &Bs[cur*4096 + rb*BK2 + ((lg ^ ((rb >> 1) & 3)) << 3)]);
    }
    #pragma unroll
    for (int mi = 0; mi < 4; ++mi)
      #pragma unroll
      for (int ni = 0; ni < 4; ++ni)
        acc[mi][ni] = __builtin_amdgcn_mfma_f32_16x16x32_bf16(af[mi], bfr[ni], acc[mi][ni], 0, 0, 0);

    __syncthreads();   // drains prefetch (implicit vmcnt0) + LDS reads
  }
  #undef STAGE2

  int r4 = lg * 4;
  if (n0 >= 2*DMODEL) {
    // ---- V block (uniform c==2): LDS transpose -> coalesced Vt stores
    int hd0 = n0 - 2*DMODEL;
    #pragma unroll
    for (int mi = 0; mi < 4; ++mi) {
      #pragma unroll
      for (int ni = 0; ni < 4; ++ni) {
        int col = wn + ni*16 + ln;                 // hd_local
        float bias = bqkv[(hd0 + col)*3 + 2];
        int rb = wm + mi*16 + r4;                  // t_local base (mult of 4)
        ushort4 pk4;
        pk4.x = f2bf(acc[mi][ni][0] + bias);
        pk4.y = f2bf(acc[mi][ni][1] + bias);
        pk4.z = f2bf(acc[mi][ni][2] + bias);
        pk4.w = f2bf(acc[mi][ni][3] + bias);
        *reinterpret_cast<ushort4*>(&Ep[col*EPSTRIDE + rb]) = pk4;
      }
    }
    __syncthreads();
    int n = m0 >> 11, t0 = m0 & 2047;
    #pragma unroll
    for (int pass = 0; pass < 8; ++pass) {
      int hdl = pass*16 + (tid >> 4);
      int seg = tid & 15;
      bf16x8 v = *reinterpret_cast<const bf16x8*>(&Ep[hdl*EPSTRIDE + seg*8]);
      int hd = hd0 + hdl, h = hd >> 6, d = hd & 63;
      *reinterpret_cast<bf16x8*>(
          &Vt[(((size_t)(n*NHEADS + h)*HDIM + d) << 11) + t0 + seg*8]) = v;
    }
  } else {
    // ---- Q/K blocks (c==0/1): 32B-contiguous per 16-lane group
    #pragma unroll
    for (int mi = 0; mi < 4; ++mi) {
      #pragma unroll
      for (int ni = 0; ni < 4; ++ni) {
        int nc = n0 + wn + ni*16 + ln;
        int c  = nc >> 10;
        int hd = nc & 1023;
        int h = hd >> 6, d = hd & 63;
        float bias = bqkv[hd*3 + c];
        float qs = (c == 0) ? QSCALE : 1.0f;   // fold softmax scale into Q
        #pragma unroll
        for (int j = 0; j < 4; ++j) {
          int m = m0 + wm + mi*16 + r4 + j;
          int n = m >> 11, t = m & 2047;
          unsigned short val = f2bf((acc[mi][ni][j] + bias) * qs);
          size_t nh = (size_t)(n*NHEADS + h);
          if (c == 0) Qb[((nh*SEQ + t) << 6) + d] = val;
          else        Kb[((nh*SEQ + t) << 6) + d] = val;
        }
      }
    }
  }
}

// ---------------------------------------------------------------- attention
// R13: R12's 3-buffer counted-vmcnt pipeline, but kv-loop UNROLLED x3 so the
// buffer index is a compile-time literal in every tile -> all LDS addresses
// collapse to {one per-lane VGPR base + 16-bit immediate}; per-tile address
// VALU ~0 (R12: VALUBusy 47% was dominated by re-materialized addressing).
// + T5 setprio around MFMA clusters, T17 max3-friendly max tree.
// Ledger identical to R12: write buf (t+2)%3 vs read buf t%3 disjoint;
// vmcnt(2) at tile end = tile t+1 landed, t+2 stays in flight.
#define PROW    88                  // P row stride, bf16 elems (176 B)
#define POFF    49152               // P regions start (after 3 staging bufs)
#define PBYTES  2816                // 16 rows x 176 B per wave
#define OREGION 4352                // epilogue obuf: 16 x 68 f32 (reuses staging)
__launch_bounds__(512)
__global__ void attn_kernel(const unsigned short* __restrict__ Qb,
                            const unsigned short* __restrict__ Kb,
                            const unsigned short* __restrict__ Vt,
                            float* __restrict__ out) {
  __shared__ __align__(16) unsigned char smem[POFF + 8*PBYTES]; // 71680 B
  int tid = threadIdx.x;
  int w = tid >> 6, l = tid & 63;
  int ln = l & 15, lg = l >> 4;

  unsigned short* Pw  = (unsigned short*)(smem + POFF + w * PBYTES);
  float*          obw = (float*)         (smem + w * OREGION); // post-loop only

  // XCD clustering: 512 blocks, 8 XCDs -> each XCD owns 4 heads
  int fid  = blockIdx.x;
  int xcd  = fid & 7, idx = fid >> 3;       // idx 0..63
  int bh   = xcd * 4 + (idx >> 4);          // 0..31
  int qblk = idx & 15;                      // 0..15 (128 q-rows each)
  int q0   = qblk * 128 + w * 16;

  const unsigned short* Qh = Qb + (size_t)bh * SEQ * HDIM;
  const unsigned short* Kh = Kb + (size_t)bh * SEQ * HDIM;
  const unsigned short* Vh = Vt + (size_t)bh * HDIM * SEQ;

  // staging mapping: 512 threads cover one 64x64 bf16 tile in ONE call
  int srow = w*8 + (l >> 3);      // row 0..63
  int sseg = (l & 7) ^ (srow & 7);// inverse-swizzled 16B segment

  // Q B-fragments (col = q = ln), d-windows dw=0,1
  bf16x8 qf[2];
  #pragma unroll
  for (int dw = 0; dw < 2; ++dw)
    qf[dw] = *reinterpret_cast<const bf16x8*>(&Qh[(size_t)(q0 + ln)*HDIM + dw*32 + lg*8]);

  const f32x4 zero4 = {0.f, 0.f, 0.f, 0.f};
  f32x4 o[4];
  #pragma unroll
  for (int db = 0; db < 4; ++db) o[db] = zero4;
  f32x4 psum4 = zero4;
  float mrow = -INFINITY;

  int xorE = (ln & 7) << 3;        // element-index XOR for swizzled ds_read
  // loop-invariant per-lane byte offsets (K and V share row stride 128 B)
  int coff0 = (((     lg*8) ^ xorE)) * 2;   // d-window 0 column bytes
  int coff1 = (((32 + lg*8) ^ xorE)) * 2;   // d-window 1 column bytes
  int rbyte = ln * 128;                      // fragment row base bytes
  const unsigned char* kv0 = smem + rbyte + coff0;  // + CUR*16384 + kb*2048 (+8192+db*2048 for V)
  const unsigned char* kv1 = smem + rbyte + coff1;

  // STAGE one 64-key tile into buffer BUF: K[key][d] + V[d][key]
  #define STAGE(BUF, KEY0)                                                    \
  do {                                                                        \
    async_copy16(smem + (BUF)*16384 + w*1024,                                 \
                 &Kh[(size_t)((KEY0) + srow)*HDIM + sseg*8]);                 \
    async_copy16(smem + (BUF)*16384 + 8192 + w*1024,                          \
                 &Vh[(size_t)srow*SEQ + (KEY0) + sseg*8]);                    \
  } while (0)

  STAGE(0, 0);
  STAGE(1, 64);
  asm volatile("s_waitcnt vmcnt(2)" ::: "memory");   // tile 0 landed
  __builtin_amdgcn_s_barrier();
  asm volatile("" ::: "memory");

  // one 64-key tile; CUR/NXTB are compile-time literals
  #define TILE(KV, CUR, DOSTAGE, NXTB)                                        \
  do {                                                                        \
    if (DOSTAGE) STAGE(NXTB, ((KV) + 2) * 64);                                \
    /* ---- S^T: 4 key-blocks x 2 d-windows (base + imm addressing) */        \
    f32x4 s[4];                                                               \
    __builtin_amdgcn_s_setprio(1);                                            \
    _Pragma("unroll")                                                         \
    for (int kb = 0; kb < 4; ++kb) {                                          \
      bf16x8 k0 = *reinterpret_cast<const bf16x8*>(kv0 + (CUR)*16384 + kb*2048);\
      bf16x8 k1 = *reinterpret_cast<const bf16x8*>(kv1 + (CUR)*16384 + kb*2048);\
      f32x4 t0 = __builtin_amdgcn_mfma_f32_16x16x32_bf16(k0, qf[0], zero4, 0, 0, 0);\
      s[kb]    = __builtin_amdgcn_mfma_f32_16x16x32_bf16(k1, qf[1], t0,    0, 0, 0);\
    }                                                                         \
    __builtin_amdgcn_s_setprio(0);                                            \
    /* ---- per-lane local max (max3-friendly nesting) */                     \
    f32x4 m4 = vmax4(vmax4(s[0], s[1]), vmax4(s[2], s[3]));                   \
    float localmax = fmaxf(fmaxf(fmaxf(m4[0], m4[1]), m4[2]), m4[3]);         \
    /* ---- T13 defer-max: full reduce+rescale only when max grows */         \
    if (!__all(localmax <= mrow + 8.f)) {                                     \
      float pm = localmax;                                                    \
      pm = fmaxf(pm, __shfl_xor(pm, 16));                                     \
      pm = fmaxf(pm, __shfl_xor(pm, 32));                                     \
      float mn  = fmaxf(mrow, pm);                                            \
      float scl = __builtin_amdgcn_exp2f(mrow - mn);                          \
      mrow = mn;                                                              \
      psum4 *= scl;                                                           \
      _Pragma("unroll")                                                       \
      for (int db = 0; db < 4; ++db)                                          \
        _Pragma("unroll")                                                     \
        for (int r = 0; r < 4; ++r) o[db][r] *= scl;                          \
    }                                                                         \
    /* ---- P = exp2(S - m); per-lane partial sums */                         \
    _Pragma("unroll")                                                         \
    for (int kb = 0; kb < 4; ++kb) {                                          \
      _Pragma("unroll")                                                       \
      for (int r = 0; r < 4; ++r)                                             \
        s[kb][r] = __builtin_amdgcn_exp2f(s[kb][r] - mrow);                   \
      psum4 += s[kb];                                                         \
    }                                                                         \
    /* ---- P -> LDS via v_cvt_pk_bf16_f32 (T12) */                           \
    _Pragma("unroll")                                                         \
    for (int kb = 0; kb < 4; ++kb) {                                          \
      uint2 pk;                                                               \
      asm("v_cvt_pk_bf16_f32 %0, %1, %2" : "=v"(pk.x) : "v"(s[kb][0]), "v"(s[kb][1]));\
      asm("v_cvt_pk_bf16_f32 %0, %1, %2" : "=v"(pk.y) : "v"(s[kb][2]), "v"(s[kb][3]));\
      *reinterpret_cast<uint2*>(&Pw[ln*PROW + kb*16 + 4*lg]) = pk;            \
    }                                                                         \
    /* ---- PV: A = V^T frags, B = P^T from LDS */                            \
    _Pragma("unroll")                                                         \
    for (int kw = 0; kw < 2; ++kw) {                                          \
      bf16x8 pb = *reinterpret_cast<const bf16x8*>(&Pw[ln*PROW + kw*32 + lg*8]);\
      const unsigned char* vb = (kw == 0) ? kv0 : kv1;                        \
      __builtin_amdgcn_s_setprio(1);                                          \
      _Pragma("unroll")                                                       \
      for (int db = 0; db < 4; ++db) {                                        \
        bf16x8 vfr = *reinterpret_cast<const bf16x8*>(                        \
            vb + (CUR)*16384 + 8192 + db*2048);                               \
        o[db] = __builtin_amdgcn_mfma_f32_16x16x32_bf16(vfr, pb, o[db], 0, 0, 0);\
      }                                                                       \
      __builtin_amdgcn_s_setprio(0);                                          \
    }                                                                         \
    /* ---- counted wait: tile KV+1 landed; KV+2 stays in flight */           \
    if (DOSTAGE) asm volatile("s_waitcnt vmcnt(2)" ::: "memory");             \
    else         asm volatile("s_waitcnt vmcnt(0)" ::: "memory");             \
    __builtin_amdgcn_s_barrier();                                             \
    asm volatile("" ::: "memory");                                            \
  } while (0)

  for (int kv = 0; kv < 30; kv += 3) {
    TILE(kv,     0, 1, 2);
    TILE(kv + 1, 1, 1, 0);
    TILE(kv + 2, 2, 1, 1);
  }
  TILE(30, 0, 0, 0);
  TILE(31, 1, 0, 0);
  #undef TILE
  #undef STAGE

  // ---- post-loop: row-sum reduce (once), normalize, transpose, store
  float ls = (psum4[0] + psum4[1]) + (psum4[2] + psum4[3]);
  ls += __shfl_xor(ls, 16);
  ls += __shfl_xor(ls, 32);
  float inv = 1.f / ls;

  #pragma unroll
  for (int db = 0; db < 4; ++db)
    #pragma unroll
    for (int r = 0; r < 4; ++r)
      obw[ln*68 + db*16 + 4*lg + r] = o[db][r] * inv;
  asm volatile("s_waitcnt lgkmcnt(0)" ::: "memory");
  int n = bh >> 4, h = bh & 15;
  #pragma unroll
  for (int p = 0; p < 4; ++p) {
    int q = p*4 + lg;
    f32x4 vv = *reinterpret_cast<const f32x4*>(&obw[q*68 + ln*4]);
    *reinterpret_cast<f32x4*>(
        &out[((size_t)(n*SEQ + q0 + q))*DMODEL + h*HDIM + ln*4]) = vv;
  }
}

// ---------------------------------------------------------------- launcher
extern "C" void kernel_launch(void* const* d_in, const int* in_sizes, int n_in,
                              void* d_out, int out_size, void* d_ws, size_t ws_size,
                              hipStream_t stream) {
  const float* x    = (const float*)d_in[0];
  // d_in[1] = mask: constant shift along query axis inside softmax -> no-op
  const float* Wq   = (const float*)d_in[2];
  const float* bq   = (const float*)d_in[3];
  float* out = (float*)d_out;

  unsigned short* xb = (unsigned short*)d_ws;                    // [4096][1024]
  unsigned short* wt = xb + (size_t)MTOT*KTOT;                   // [3072][1024]
  unsigned short* Qb = wt + (size_t)NTOT*KTOT;                   // [32][2048][64]
  unsigned short* Kb = Qb + (size_t)NB*NHEADS*SEQ*HDIM;          // [32][2048][64]
  unsigned short* Vt = Kb + (size_t)NB*NHEADS*SEQ*HDIM;          // [32][64][2048]

  convert_x_kernel<<<(MTOT*KTOT/8)/256, 256, 0, stream>>>(x, xb);
  transpose_w_kernel<<<dim3(NTOT/64, KTOT/64), 256, 0, stream>>>(Wq, wt);
  qkv_gemm_kernel<<<dim3(NBX, NBY), 256, 0, stream>>>(xb, wt, bq, Qb, Kb, Vt);
  attn_kernel<<<512, 512, 0, stream>>>(Qb, Kb, Vt, out);
}